// Round 4
// baseline (309.456 us; speedup 1.0000x reference)
//
#include <hip/hip_runtime.h>
#include <hip/hip_fp16.h>
#include <cstdint>
#include <type_traits>

#define THREADS 256
#define NBLK 64     // blocks for hist/scatter
#define BPAD 512    // padded bucket count (dst>>8; N<=131072)
#define LINBLK 640  // blocks for lin_attn (layer 1)
#define ECAP 1024   // staged edges per chunk (32-node block; Poisson mean ~352)

typedef _Float16 half8 __attribute__((ext_vector_type(8)));
typedef float v4f __attribute__((ext_vector_type(4)));

// ---------------- CSR build: bucket sort, no global atomics ----------------
// block 0 also zero-inits pool/root (used much later; no ordering hazard).
__global__ __launch_bounds__(256) void hist_kernel(const int* __restrict__ dst_e,
                                                   int* __restrict__ hist, int E, int chunk,
                                                   float* __restrict__ pool, int* __restrict__ root,
                                                   int G) {
  __shared__ int hcnt[BPAD];
  int t = threadIdx.x, blk = blockIdx.x;
  if (blk == 0) {
    for (int i = t; i < G * 64; i += 256) pool[i] = 0.0f;
    for (int i = t; i < G; i += 256) root[i] = 0x7fffffff;
  }
  for (int i = t; i < BPAD; i += 256) hcnt[i] = 0;
  __syncthreads();
  int s = blk * chunk, e = s + chunk;
  if (e > E) e = E;
  for (int i = s + t; i < e; i += 256) atomicAdd(&hcnt[dst_e[i] >> 8], 1);
  __syncthreads();
  for (int b = t; b < BPAD; b += 256) hist[b * NBLK + blk] = hcnt[b];
}

__global__ __launch_bounds__(256) void hscan_kernel(int* __restrict__ hist) {
  __shared__ int part[256];
  const int PER = (BPAD * NBLK) / 256;  // 128
  int t = threadIdx.x;
  int base = t * PER;
  int sum = 0;
  for (int k = 0; k < PER; k++) sum += hist[base + k];
  part[t] = sum;
  __syncthreads();
  int own = sum;
  for (int off = 1; off < 256; off <<= 1) {
    int v = (t >= off) ? part[t - off] : 0;
    __syncthreads();
    part[t] += v;
    __syncthreads();
  }
  int run = part[t] - own;
  for (int k = 0; k < PER; k++) {
    int h = hist[base + k];
    hist[base + k] = run;
    run += h;
  }
}

// scatter edges into bucket-partitioned ebuf, packed (src<<8)|(dst&255).
__global__ __launch_bounds__(256) void scatter_kernel(const int* __restrict__ src_e,
                                                      const int* __restrict__ dst_e,
                                                      const int* __restrict__ hist,
                                                      unsigned int* __restrict__ ebuf,
                                                      int E, int chunk) {
  __shared__ int cur[BPAD];
  int t = threadIdx.x, blk = blockIdx.x;
  for (int b = t; b < BPAD; b += 256) cur[b] = hist[b * NBLK + blk];
  __syncthreads();
  int s = blk * chunk, e = s + chunk;
  if (e > E) e = E;
  for (int i = s + t; i < e; i += 256) {
    int d = dst_e[i];
    unsigned int sv = (unsigned int)src_e[i];
    int slot = atomicAdd(&cur[d >> 8], 1);
    ebuf[slot] = (sv << 8) | (unsigned int)(d & 255);
  }
}

// per-bucket CSR finalize: row_start + csr_src (+self-loop in last slot).
__global__ __launch_bounds__(256) void build_kernel(const unsigned int* __restrict__ ebuf,
                                                    const int* __restrict__ hist,
                                                    int* __restrict__ row_start,
                                                    int* __restrict__ csr_src,
                                                    int N, int E) {
  __shared__ int counts[256];
  __shared__ int sc[256];
  __shared__ int curw[256];
  int t = threadIdx.x, b = blockIdx.x;
  int nbase = b * 256;
  int ebase = hist[b * NBLK];
  int eend = hist[(b + 1) * NBLK];
  counts[t] = 0;
  __syncthreads();
  int ecount = eend - ebase;
  for (int i = t; i < ecount; i += 256)
    atomicAdd(&counts[ebuf[ebase + i] & 255u], 1);
  __syncthreads();
  int n = nbase + t;
  int val = (n < N) ? counts[t] + 1 : 0;  // +1 self-loop
  sc[t] = val;
  __syncthreads();
  int own = val;
  for (int off = 1; off < 256; off <<= 1) {
    int v = (t >= off) ? sc[t - off] : 0;
    __syncthreads();
    sc[t] += v;
    __syncthreads();
  }
  int myloc = sc[t] - own;  // exclusive
  int rowb = ebase + nbase;  // prior real edges + prior self-loops
  if (n < N) {
    row_start[n] = rowb + myloc;
    csr_src[rowb + myloc + counts[t]] = n;  // self-loop in last slot
    if (n == N - 1) row_start[N] = rowb + myloc + counts[t] + 1;
  }
  curw[t] = rowb + myloc;
  __syncthreads();
  for (int i = t; i < ecount; i += 256) {
    unsigned int ev = ebuf[ebase + i];
    int pos = atomicAdd(&curw[ev & 255u], 1);
    csr_src[pos] = (int)(ev >> 8);
  }
}

// ---------------- linear + attention scalars (MFMA), layer 1 ----------------
// h = in @ W via v_mfma_f32_16x16x32_f16. Layouts (m89/m91/m120):
//   A[m=lane&15][k=quad*8+j]; B[k=quad*8+j][n=lane&15];
//   D: row(m)=quad*4+reg, col(n)=lane&15.
// Transpose LDS padded to stride 72 halves (144B): 2-way banks on float4 reads.
template <int K, typename TIN>
__global__ __launch_bounds__(256) void lin_attn_kernel(
    const TIN* __restrict__ in, const float* __restrict__ W,
    const float* __restrict__ a_src, const float* __restrict__ a_dst,
    __half2* __restrict__ h2, float* __restrict__ as_, float* __restrict__ ad_,
    int N, int nwaves) {
  constexpr int NKC = K / 32;
  __shared__ _Float16 sh[4][16 * 72];  // per-wave transpose buffer (padded)
  const int t = threadIdx.x;
  const int lane = t & 63, w = t >> 6;
  const int col = lane & 15, quad = lane >> 4;
  const int wid = blockIdx.x * 4 + w;

  // B fragments from W (fp32 -> fp16), reused across all tiles
  half8 bf[4][NKC];
#pragma unroll
  for (int nt = 0; nt < 4; nt++)
#pragma unroll
    for (int kc = 0; kc < NKC; kc++) {
      half8 v;
#pragma unroll
      for (int j = 0; j < 8; j++)
        v[j] = (_Float16)W[(kc * 32 + quad * 8 + j) * 64 + nt * 16 + col];
      bf[nt][kc] = v;
    }
  float sa[4], sd[4];
#pragma unroll
  for (int nt = 0; nt < 4; nt++) {
    sa[nt] = a_src[nt * 16 + col];
    sd[nt] = a_dst[nt * 16 + col];
  }

  const int ntiles = (N + 15) >> 4;
  for (int tile = wid; tile < ntiles; tile += nwaves) {
    const int nb = tile << 4;
    int nodeA = nb + col;
    if (nodeA >= N) nodeA = N - 1;
    const TIN* arow = in + (size_t)nodeA * K + quad * 8;

    v4f acc[4];
#pragma unroll
    for (int nt = 0; nt < 4; nt++) acc[nt] = (v4f){0.f, 0.f, 0.f, 0.f};

#pragma unroll
    for (int kc = 0; kc < NKC; kc++) {
      half8 a;
      if constexpr (std::is_same<TIN, float>::value) {
        float4 f0 = *(const float4*)(arow + kc * 32);
        float4 f1 = *(const float4*)(arow + kc * 32 + 4);
        a[0] = (_Float16)f0.x; a[1] = (_Float16)f0.y;
        a[2] = (_Float16)f0.z; a[3] = (_Float16)f0.w;
        a[4] = (_Float16)f1.x; a[5] = (_Float16)f1.y;
        a[6] = (_Float16)f1.z; a[7] = (_Float16)f1.w;
      } else {
        a = *(const half8*)(arow + kc * 32);
      }
#pragma unroll
      for (int nt = 0; nt < 4; nt++)
        acc[nt] = __builtin_amdgcn_mfma_f32_16x16x32_f16(a, bf[nt][kc], acc[nt], 0, 0, 0);
    }

    // attention scalars: reduce over the col group
    float ps[4], pd[4];
#pragma unroll
    for (int r = 0; r < 4; r++) { ps[r] = 0.f; pd[r] = 0.f; }
#pragma unroll
    for (int nt = 0; nt < 4; nt++)
#pragma unroll
      for (int r = 0; r < 4; r++) {
        ps[r] += acc[nt][r] * sa[nt];
        pd[r] += acc[nt][r] * sd[nt];
      }
#pragma unroll
    for (int r = 0; r < 4; r++)
#pragma unroll
      for (int m = 1; m < 16; m <<= 1) {
        ps[r] += __shfl_xor(ps[r], m);
        pd[r] += __shfl_xor(pd[r], m);
      }
    if (col == 0) {
#pragma unroll
      for (int r = 0; r < 4; r++) {
        int node = nb + quad * 4 + r;
        if (node < N) { as_[node] = ps[r]; ad_[node] = pd[r]; }
      }
    }

    // h2 store via wave-private LDS transpose (no barrier: same wave r/w)
#pragma unroll
    for (int nt = 0; nt < 4; nt++)
#pragma unroll
      for (int r = 0; r < 4; r++)
        sh[w][(quad * 4 + r) * 72 + nt * 16 + col] = (_Float16)acc[nt][r];
    int nr = lane >> 2, c4 = lane & 3;
    float4 v0 = *(float4*)&sh[w][nr * 72 + c4 * 16];
    float4 v1 = *(float4*)&sh[w][nr * 72 + c4 * 16 + 8];
    int node = nb + nr;
    if (node < N) {
      *(float4*)&h2[(size_t)node * 32 + c4 * 8] = v0;
      *(float4*)&h2[(size_t)node * 32 + c4 * 8 + 4] = v1;
    }
  }
}

// ---------------- LDS-staged agg inner loop, 8-deep gather pipeline ----------
// Block's 32 nodes own a contiguous CSR slice. Stage src indices + as_
// scores into LDS cooperatively. Octet loop then issues ONLY h-row gathers,
// 8 in flight per wave before the first use (the gathers depend solely on
// LDS idx reads, so the compiler hoists all 8 issues ahead of exp/FMA).
// Clamped tail slots re-read a resident line: cheap.
__device__ __forceinline__ void agg_block_stage(
    const float4* __restrict__ h4, const float* __restrict__ as_in,
    const int* __restrict__ csr_src, int* __restrict__ s_src,
    float* __restrict__ s_as, int t, int co,
    int e0, int eEnd, int rs, int re, float adn,
    float4& A0, float4& A1, float& den) {
  for (int cs = e0; cs < eEnd; cs += ECAP) {
    int ce = cs + ECAP; if (ce > eEnd) ce = eEnd;
    int cnt = ce - cs;
    __syncthreads();  // protect LDS reuse across chunks
    for (int i = t; i < cnt; i += 256) {
      int s = csr_src[cs + i];
      s_src[i] = s;
      s_as[i] = as_in[s];
    }
    __syncthreads();
    int a0 = rs > cs ? rs : cs;
    int a1 = re < ce ? re : ce;
    for (int s = a0; s < a1; s += 8) {
      int idx[8];
#pragma unroll
      for (int j = 0; j < 8; j++) {
        int sj = s + j;
        idx[j] = ((sj < a1) ? sj : (a1 - 1)) - cs;
      }
      // issue all 8 gathers before any use
      float4 hv[8];
#pragma unroll
      for (int j = 0; j < 8; j++) hv[j] = h4[(size_t)s_src[idx[j]] * 8 + co];
      float cf[8];
#pragma unroll
      for (int j = 0; j < 8; j++) {
        float e = s_as[idx[j]] + adn;
        e = fmaxf(e, 0.2f * e);  // leaky_relu(0.2)
        cf[j] = (s + j < a1) ? __expf(e) : 0.f;
      }
#pragma unroll
      for (int j = 0; j < 8; j++) {
        const __half2* hp = (const __half2*)&hv[j];
        float2 f0 = __half22float2(hp[0]);
        float2 f1 = __half22float2(hp[1]);
        float2 f2 = __half22float2(hp[2]);
        float2 f3 = __half22float2(hp[3]);
        float c = cf[j];
        den += c;
        A0.x += c * f0.x; A0.y += c * f0.y; A0.z += c * f1.x; A0.w += c * f1.y;
        A1.x += c * f2.x; A1.y += c * f2.y; A1.z += c * f3.x; A1.w += c * f3.y;
      }
    }
  }
}

// finish one node: normalize + bias + relu -> 8 fp16 (same rounding as before)
__device__ __forceinline__ void agg_finish(const float4& A0, const float4& A1,
                                           float den, const float* __restrict__ bprev,
                                           int co, _Float16* o) {
  float inv = 1.0f / (den + 1e-16f);
  float4 b0 = *(const float4*)&bprev[co * 8];
  float4 b1 = *(const float4*)&bprev[co * 8 + 4];
  o[0] = (_Float16)fmaxf(A0.x * inv + b0.x, 0.f);
  o[1] = (_Float16)fmaxf(A0.y * inv + b0.y, 0.f);
  o[2] = (_Float16)fmaxf(A0.z * inv + b0.z, 0.f);
  o[3] = (_Float16)fmaxf(A0.w * inv + b0.w, 0.f);
  o[4] = (_Float16)fmaxf(A1.x * inv + b1.x, 0.f);
  o[5] = (_Float16)fmaxf(A1.y * inv + b1.y, 0.f);
  o[6] = (_Float16)fmaxf(A1.z * inv + b1.z, 0.f);
  o[7] = (_Float16)fmaxf(A1.w * inv + b1.w, 0.f);
}

// ---------------- fused agg (layer L) + lin (layer L+1) ----------------
// Block = 32 nodes = two 16-node MFMA tiles. Phase A0: stage edge slice in
// LDS. Phase A: 4 waves aggregate 8 nodes each into padded LDS tile.
// Phase B: waves 0,1 run the 16x64x64 MFMA; h2/as/ad written for next layer.
__global__ __launch_bounds__(256) void agg_lin_kernel(
    const __half2* __restrict__ h2in, const float* __restrict__ as_in,
    const float* __restrict__ ad_in, const int* __restrict__ csr_src,
    const int* __restrict__ row_start, const float* __restrict__ bprev,
    const float* __restrict__ W, const float* __restrict__ a_src,
    const float* __restrict__ a_dst, __half2* __restrict__ h2out,
    float* __restrict__ as_out, float* __restrict__ ad_out, int N) {
  __shared__ int s_src[ECAP];
  __shared__ float s_as[ECAP];
  __shared__ _Float16 shh[32][72];     // agg output tile (padded)
  __shared__ _Float16 sht[2][16 * 72]; // phase-B transpose (wave-private)
  const int t = threadIdx.x;
  const int lane = t & 63, w = t >> 6;
  const int base = blockIdx.x * 32;

  // ---- phase A: aggregate 32 nodes (1 per octet), edges staged in LDS ----
  {
    const int ng = lane >> 3, co = lane & 7;
    const int ln = w * 8 + ng;
    int n = base + ln;
    int nc = (n < N) ? n : (N - 1);  // clamp: redundant work, guarded stores
    int rs = row_start[nc], re = row_start[nc + 1];
    float adn = ad_in[nc];
    int nend = base + 32; if (nend > N) nend = N;
    int e0 = row_start[base], eEnd = row_start[nend];
    const float4* h4 = (const float4*)h2in;
    float4 A0 = make_float4(0.f, 0.f, 0.f, 0.f);
    float4 A1 = make_float4(0.f, 0.f, 0.f, 0.f);
    float den = 0.f;
    agg_block_stage(h4, as_in, csr_src, s_src, s_as, t, co,
                    e0, eEnd, rs, re, adn, A0, A1, den);
    _Float16 o[8];
    agg_finish(A0, A1, den, bprev, co, o);
    *(float4*)&shh[ln][co * 8] = *(float4*)o;
  }
  __syncthreads();
  if (w >= 2) return;

  // ---- phase B: lin for tile w (16 nodes), wave-per-tile ----
  const int col = lane & 15, quad = lane >> 4;
  half8 bf[4][2];
  float sa[4], sd[4];
#pragma unroll
  for (int nt = 0; nt < 4; nt++) {
#pragma unroll
    for (int kc = 0; kc < 2; kc++) {
      half8 v;
#pragma unroll
      for (int j = 0; j < 8; j++)
        v[j] = (_Float16)W[(kc * 32 + quad * 8 + j) * 64 + nt * 16 + col];
      bf[nt][kc] = v;
    }
    sa[nt] = a_src[nt * 16 + col];
    sd[nt] = a_dst[nt * 16 + col];
  }

  const int nb = base + w * 16;
  v4f acc[4];
#pragma unroll
  for (int nt = 0; nt < 4; nt++) acc[nt] = (v4f){0.f, 0.f, 0.f, 0.f};
#pragma unroll
  for (int kc = 0; kc < 2; kc++) {
    half8 a = *(const half8*)&shh[w * 16 + col][kc * 32 + quad * 8];
#pragma unroll
    for (int nt = 0; nt < 4; nt++)
      acc[nt] = __builtin_amdgcn_mfma_f32_16x16x32_f16(a, bf[nt][kc], acc[nt], 0, 0, 0);
  }

  float ps[4], pd[4];
#pragma unroll
  for (int r = 0; r < 4; r++) { ps[r] = 0.f; pd[r] = 0.f; }
#pragma unroll
  for (int nt = 0; nt < 4; nt++)
#pragma unroll
    for (int r = 0; r < 4; r++) {
      ps[r] += acc[nt][r] * sa[nt];
      pd[r] += acc[nt][r] * sd[nt];
    }
#pragma unroll
  for (int r = 0; r < 4; r++)
#pragma unroll
    for (int m = 1; m < 16; m <<= 1) {
      ps[r] += __shfl_xor(ps[r], m);
      pd[r] += __shfl_xor(pd[r], m);
    }
  if (col == 0) {
#pragma unroll
    for (int r = 0; r < 4; r++) {
      int node = nb + quad * 4 + r;
      if (node < N) { as_out[node] = ps[r]; ad_out[node] = pd[r]; }
    }
  }

#pragma unroll
  for (int nt = 0; nt < 4; nt++)
#pragma unroll
    for (int r = 0; r < 4; r++)
      sht[w][(quad * 4 + r) * 72 + nt * 16 + col] = (_Float16)acc[nt][r];
  int nr = lane >> 2, c4 = lane & 3;
  float4 v0 = *(float4*)&sht[w][nr * 72 + c4 * 16];
  float4 v1 = *(float4*)&sht[w][nr * 72 + c4 * 16 + 8];
  int node = nb + nr;
  if (node < N) {
    *(float4*)&h2out[(size_t)node * 32 + c4 * 8] = v0;
    *(float4*)&h2out[(size_t)node * 32 + c4 * 8 + 4] = v1;
  }
}

// ---------------- fused agg (layer 3) + global max pool + root ----------------
__global__ __launch_bounds__(256) void agg_pool_kernel(
    const __half2* __restrict__ h2in, const float* __restrict__ as_in,
    const float* __restrict__ ad_in, const int* __restrict__ csr_src,
    const int* __restrict__ row_start, const float* __restrict__ bprev,
    const int* __restrict__ batch, float* __restrict__ pool,
    int* __restrict__ root, int N) {
  __shared__ int s_src[ECAP];
  __shared__ float s_as[ECAP];
  __shared__ float red[4][64];
  const int t = threadIdx.x;
  const int lane = t & 63, w = t >> 6;
  const int ng = lane >> 3, co = lane & 7;
  const int ln = w * 8 + ng;
  const int base = blockIdx.x * 32;
  int n = base + ln;
  int nc = (n < N) ? n : (N - 1);
  int rs = row_start[nc], re = row_start[nc + 1];
  float adn = ad_in[nc];
  int nend = base + 32; if (nend > N) nend = N;
  int e0 = row_start[base], eEnd = row_start[nend];
  const float4* h4 = (const float4*)h2in;
  float4 A0 = make_float4(0.f, 0.f, 0.f, 0.f);
  float4 A1 = make_float4(0.f, 0.f, 0.f, 0.f);
  float den = 0.f;
  agg_block_stage(h4, as_in, csr_src, s_src, s_as, t, co,
                  e0, eEnd, rs, re, adn, A0, A1, den);
  // round through fp16 to keep bit-identical behavior with the fp16 handoff
  _Float16 o[8];
  agg_finish(A0, A1, den, bprev, co, o);
  float ov[8];
#pragma unroll
  for (int j = 0; j < 8; j++) ov[j] = (float)o[j];

  int g = batch[nc];
  if (co == 0 && n < N) {
    if (n == 0 || batch[n - 1] != g) atomicMin(&root[g], n);
  }

  int bstart = base;
  int bend = base + 31; if (bend >= N) bend = N - 1;
  int gfirst = batch[bstart];
  int glast = batch[bend];
  if (gfirst == glast) {
    // block covers one graph: reduce 32 nodes -> 64ch, one atomic/ch.
    // clamped lanes replay node N-1 into its own graph's max: no-op.
#pragma unroll
    for (int m = 8; m < 64; m <<= 1)
#pragma unroll
      for (int j = 0; j < 8; j++) ov[j] = fmaxf(ov[j], __shfl_xor(ov[j], m));
    if (ng == 0)
#pragma unroll
      for (int j = 0; j < 8; j++) red[w][co * 8 + j] = ov[j];
    __syncthreads();
    if (t < 64) {
      float m0 = fmaxf(red[0][t], red[1][t]);
      float m1 = fmaxf(red[2][t], red[3][t]);
      atomicMax((int*)&pool[(size_t)gfirst * 64 + t], __float_as_int(fmaxf(m0, m1)));
    }
  } else {
    // graph boundary inside block (~G blocks total): per-lane atomics
#pragma unroll
    for (int j = 0; j < 8; j++)
      if (n < N) atomicMax((int*)&pool[(size_t)g * 64 + co * 8 + j], __float_as_int(ov[j]));
  }
}

// ---------------- final fused MLP head (wave per graph) ----------------
__global__ void final_kernel(const float* __restrict__ pool, const int* __restrict__ root,
                             const float* __restrict__ x,
                             const float* __restrict__ lin0_W, const float* __restrict__ lin0_b,
                             const float* __restrict__ linnews_W, const float* __restrict__ linnews_b,
                             const float* __restrict__ lin1_W, const float* __restrict__ lin1_b,
                             float* __restrict__ out, int G, int N) {
  int t = threadIdx.x;
  int lane = t & 63, w = t >> 6;
  int g = blockIdx.x * 4 + w;
  if (g >= G) return;
  float hp = 0.f;
  for (int k = 0; k < 64; k++) hp += pool[(size_t)g * 64 + k] * lin0_W[k * 64 + lane];
  hp = fmaxf(hp + lin0_b[lane], 0.f);
  int r = root[g]; if (r > N - 1) r = N - 1; if (r < 0) r = 0;
  float nw = 0.f;
  for (int k = 0; k < 128; k++) nw += x[(size_t)r * 128 + k] * linnews_W[k * 64 + lane];
  nw = fmaxf(nw + linnews_b[lane], 0.f);
  float p = hp * lin1_W[lane] + nw * lin1_W[64 + lane];
  for (int k = 1; k < 64; k <<= 1) p += __shfl_xor(p, k);
  if (lane == 0) out[g] = 1.0f / (1.0f + __expf(-(p + lin1_b[0])));
}

// ---------------- launch ----------------
extern "C" void kernel_launch(void* const* d_in, const int* in_sizes, int n_in,
                              void* d_out, int out_size, void* d_ws, size_t ws_size,
                              hipStream_t stream) {
  (void)n_in; (void)ws_size;
  const float* x      = (const float*)d_in[0];
  const int*   adj    = (const int*)d_in[1];
  const int*   batch  = (const int*)d_in[2];
  const float* W1     = (const float*)d_in[3];
  const float* asrc1  = (const float*)d_in[4];
  const float* adst1  = (const float*)d_in[5];
  const float* b1     = (const float*)d_in[6];
  const float* W2     = (const float*)d_in[7];
  const float* asrc2  = (const float*)d_in[8];
  const float* adst2  = (const float*)d_in[9];
  const float* b2     = (const float*)d_in[10];
  const float* W3     = (const float*)d_in[11];
  const float* asrc3  = (const float*)d_in[12];
  const float* adst3  = (const float*)d_in[13];
  const float* b3     = (const float*)d_in[14];
  const float* lnW    = (const float*)d_in[15];
  const float* lnb    = (const float*)d_in[16];
  const float* l0W    = (const float*)d_in[17];
  const float* l0b    = (const float*)d_in[18];
  const float* l1W    = (const float*)d_in[19];
  const float* l1b    = (const float*)d_in[20];
  float* outp = (float*)d_out;

  const int N = in_sizes[2];
  const int E = in_sizes[1] / 2;
  const int Etot = E + N;
  const int G = out_size;
  const int B = (N + 255) / 256;  // real buckets (<= BPAD)

  const int* src_e = adj;
  const int* dst_e = adj + E;

  uintptr_t p = (uintptr_t)d_ws;
  auto alloc = [&](size_t bytes) -> void* {
    void* r = (void*)p;
    p += (bytes + 255) & ~(size_t)255;
    return r;
  };
  int*      hist      = (int*)alloc((size_t)BPAD * NBLK * 4);
  int*      row_start = (int*)alloc((size_t)(N + 1) * 4);
  int*      csr_src   = (int*)alloc((size_t)Etot * 4);
  unsigned int* ebuf  = (unsigned int*)alloc((size_t)E * 4);
  __half2*  hA        = (__half2*)alloc((size_t)N * 32 * 4);   // h ping
  __half2*  hB        = (__half2*)alloc((size_t)N * 32 * 4);   // h pong
  float*    asA       = (float*)alloc((size_t)N * 4);
  float*    adA       = (float*)alloc((size_t)N * 4);
  float*    asB       = (float*)alloc((size_t)N * 4);
  float*    adB       = (float*)alloc((size_t)N * 4);
  float*    pool      = (float*)alloc((size_t)G * 64 * 4);
  int*      root      = (int*)alloc((size_t)G * 4);

  int chunk = (E + NBLK - 1) / NBLK;
  hist_kernel<<<dim3(NBLK), dim3(256), 0, stream>>>(dst_e, hist, E, chunk, pool, root, G);
  hscan_kernel<<<dim3(1), dim3(256), 0, stream>>>(hist);
  scatter_kernel<<<dim3(NBLK), dim3(256), 0, stream>>>(src_e, dst_e, hist, ebuf, E, chunk);
  build_kernel<<<dim3(B), dim3(256), 0, stream>>>(ebuf, hist, row_start, csr_src, N, E);

  const int aggGrid = (N + 31) / 32;
  const int nwaves = LINBLK * 4;

  // layer 1 lin (x fp32 -> h, as, ad)
  lin_attn_kernel<128, float><<<dim3(LINBLK), dim3(256), 0, stream>>>(
      x, W1, asrc1, adst1, hA, asA, adA, N, nwaves);
  // agg1 + lin2 fused (ping -> pong)
  agg_lin_kernel<<<dim3(aggGrid), dim3(256), 0, stream>>>(
      hA, asA, adA, csr_src, row_start, b1, W2, asrc2, adst2, hB, asB, adB, N);
  // agg2 + lin3 fused (pong -> ping)
  agg_lin_kernel<<<dim3(aggGrid), dim3(256), 0, stream>>>(
      hB, asB, adB, csr_src, row_start, b2, W3, asrc3, adst3, hA, asA, adA, N);
  // agg3 + pool + root fused
  agg_pool_kernel<<<dim3(aggGrid), dim3(256), 0, stream>>>(
      hA, asA, adA, csr_src, row_start, b3, batch, pool, root, N);

  // head
  final_kernel<<<dim3((G + 3) / 4), dim3(256), 0, stream>>>(
      pool, root, x, l0W, l0b, lnW, lnb, l1W, l1b, outp, G, N);
}

// Round 5
// 301.488 us; speedup vs baseline: 1.0264x; 1.0264x over previous
//
#include <hip/hip_runtime.h>
#include <hip/hip_fp16.h>
#include <cstdint>
#include <type_traits>

#define THREADS 256
#define NBLK 64     // blocks for hist/scatter
#define BPAD 512    // padded bucket count (dst>>8; N<=131072)
#define LINBLK 640  // blocks for lin_attn (layer 1)
#define ECAP 1024   // staged edges per chunk (32-node block; Poisson mean ~352)

typedef _Float16 half8 __attribute__((ext_vector_type(8)));
typedef float v4f __attribute__((ext_vector_type(4)));
typedef float v2f __attribute__((ext_vector_type(2)));

// ---------------- CSR build: bucket sort, no global atomics ----------------
// block 0 also zero-inits pool/root (used much later; no ordering hazard).
__global__ __launch_bounds__(256) void hist_kernel(const int* __restrict__ dst_e,
                                                   int* __restrict__ hist, int E, int chunk,
                                                   float* __restrict__ pool, int* __restrict__ root,
                                                   int G) {
  __shared__ int hcnt[BPAD];
  int t = threadIdx.x, blk = blockIdx.x;
  if (blk == 0) {
    for (int i = t; i < G * 64; i += 256) pool[i] = 0.0f;
    for (int i = t; i < G; i += 256) root[i] = 0x7fffffff;
  }
  for (int i = t; i < BPAD; i += 256) hcnt[i] = 0;
  __syncthreads();
  int s = blk * chunk, e = s + chunk;
  if (e > E) e = E;
  for (int i = s + t; i < e; i += 256) atomicAdd(&hcnt[dst_e[i] >> 8], 1);
  __syncthreads();
  for (int b = t; b < BPAD; b += 256) hist[b * NBLK + blk] = hcnt[b];
}

__global__ __launch_bounds__(256) void hscan_kernel(int* __restrict__ hist) {
  __shared__ int part[256];
  const int PER = (BPAD * NBLK) / 256;  // 128
  int t = threadIdx.x;
  int base = t * PER;
  int sum = 0;
  for (int k = 0; k < PER; k++) sum += hist[base + k];
  part[t] = sum;
  __syncthreads();
  int own = sum;
  for (int off = 1; off < 256; off <<= 1) {
    int v = (t >= off) ? part[t - off] : 0;
    __syncthreads();
    part[t] += v;
    __syncthreads();
  }
  int run = part[t] - own;
  for (int k = 0; k < PER; k++) {
    int h = hist[base + k];
    hist[base + k] = run;
    run += h;
  }
}

// scatter edges into bucket-partitioned ebuf, packed (src<<8)|(dst&255).
__global__ __launch_bounds__(256) void scatter_kernel(const int* __restrict__ src_e,
                                                      const int* __restrict__ dst_e,
                                                      const int* __restrict__ hist,
                                                      unsigned int* __restrict__ ebuf,
                                                      int E, int chunk) {
  __shared__ int cur[BPAD];
  int t = threadIdx.x, blk = blockIdx.x;
  for (int b = t; b < BPAD; b += 256) cur[b] = hist[b * NBLK + blk];
  __syncthreads();
  int s = blk * chunk, e = s + chunk;
  if (e > E) e = E;
  for (int i = s + t; i < e; i += 256) {
    int d = dst_e[i];
    unsigned int sv = (unsigned int)src_e[i];
    int slot = atomicAdd(&cur[d >> 8], 1);
    ebuf[slot] = (sv << 8) | (unsigned int)(d & 255);
  }
}

// per-bucket CSR finalize: row_start + csr_src (+self-loop in last slot).
__global__ __launch_bounds__(256) void build_kernel(const unsigned int* __restrict__ ebuf,
                                                    const int* __restrict__ hist,
                                                    int* __restrict__ row_start,
                                                    int* __restrict__ csr_src,
                                                    int N, int E) {
  __shared__ int counts[256];
  __shared__ int sc[256];
  __shared__ int curw[256];
  int t = threadIdx.x, b = blockIdx.x;
  int nbase = b * 256;
  int ebase = hist[b * NBLK];
  int eend = hist[(b + 1) * NBLK];
  counts[t] = 0;
  __syncthreads();
  int ecount = eend - ebase;
  for (int i = t; i < ecount; i += 256)
    atomicAdd(&counts[ebuf[ebase + i] & 255u], 1);
  __syncthreads();
  int n = nbase + t;
  int val = (n < N) ? counts[t] + 1 : 0;  // +1 self-loop
  sc[t] = val;
  __syncthreads();
  int own = val;
  for (int off = 1; off < 256; off <<= 1) {
    int v = (t >= off) ? sc[t - off] : 0;
    __syncthreads();
    sc[t] += v;
    __syncthreads();
  }
  int myloc = sc[t] - own;  // exclusive
  int rowb = ebase + nbase;  // prior real edges + prior self-loops
  if (n < N) {
    row_start[n] = rowb + myloc;
    csr_src[rowb + myloc + counts[t]] = n;  // self-loop in last slot
    if (n == N - 1) row_start[N] = rowb + myloc + counts[t] + 1;
  }
  curw[t] = rowb + myloc;
  __syncthreads();
  for (int i = t; i < ecount; i += 256) {
    unsigned int ev = ebuf[ebase + i];
    int pos = atomicAdd(&curw[ev & 255u], 1);
    csr_src[pos] = (int)(ev >> 8);
  }
}

// ---- fp8 row store: 16 fp16 (LDS transpose row segment) -> 16 fp8 e4m3 ----
// h's ONLY consumer is the agg gather; fp8 halves lines-per-edge (2 -> 1).
__device__ __forceinline__ void store_row_fp8(const _Float16* hp, unsigned char* dst) {
  unsigned int d[4];
#pragma unroll
  for (int q = 0; q < 4; q++) {
    float f0 = (float)hp[q * 4 + 0], f1 = (float)hp[q * 4 + 1];
    float f2 = (float)hp[q * 4 + 2], f3 = (float)hp[q * 4 + 3];
    unsigned int w0 = __builtin_amdgcn_cvt_pk_fp8_f32(f0, f1, 0, false);
    d[q] = __builtin_amdgcn_cvt_pk_fp8_f32(f2, f3, w0, true);
  }
  uint4 v; v.x = d[0]; v.y = d[1]; v.z = d[2]; v.w = d[3];
  *(uint4*)dst = v;
}

// ---------------- linear + attention scalars (MFMA), layer 1 ----------------
// h = in @ W via v_mfma_f32_16x16x32_f16. Layouts (m89/m91/m120):
//   A[m=lane&15][k=quad*8+j]; B[k=quad*8+j][n=lane&15];
//   D: row(m)=quad*4+reg, col(n)=lane&15.
// Transpose LDS padded to stride 72 halves: 2-way banks on vector reads.
// Output h stored fp8 e4m3 (64 B/row); attention scalars from exact f32 acc.
template <int K, typename TIN>
__global__ __launch_bounds__(256) void lin_attn_kernel(
    const TIN* __restrict__ in, const float* __restrict__ W,
    const float* __restrict__ a_src, const float* __restrict__ a_dst,
    unsigned char* __restrict__ h8, float* __restrict__ as_, float* __restrict__ ad_,
    int N, int nwaves) {
  constexpr int NKC = K / 32;
  __shared__ _Float16 sh[4][16 * 72];  // per-wave transpose buffer (padded)
  const int t = threadIdx.x;
  const int lane = t & 63, w = t >> 6;
  const int col = lane & 15, quad = lane >> 4;
  const int wid = blockIdx.x * 4 + w;

  // B fragments from W (fp32 -> fp16), reused across all tiles
  half8 bf[4][NKC];
#pragma unroll
  for (int nt = 0; nt < 4; nt++)
#pragma unroll
    for (int kc = 0; kc < NKC; kc++) {
      half8 v;
#pragma unroll
      for (int j = 0; j < 8; j++)
        v[j] = (_Float16)W[(kc * 32 + quad * 8 + j) * 64 + nt * 16 + col];
      bf[nt][kc] = v;
    }
  float sa[4], sd[4];
#pragma unroll
  for (int nt = 0; nt < 4; nt++) {
    sa[nt] = a_src[nt * 16 + col];
    sd[nt] = a_dst[nt * 16 + col];
  }

  const int ntiles = (N + 15) >> 4;
  for (int tile = wid; tile < ntiles; tile += nwaves) {
    const int nb = tile << 4;
    int nodeA = nb + col;
    if (nodeA >= N) nodeA = N - 1;
    const TIN* arow = in + (size_t)nodeA * K + quad * 8;

    v4f acc[4];
#pragma unroll
    for (int nt = 0; nt < 4; nt++) acc[nt] = (v4f){0.f, 0.f, 0.f, 0.f};

#pragma unroll
    for (int kc = 0; kc < NKC; kc++) {
      half8 a;
      if constexpr (std::is_same<TIN, float>::value) {
        float4 f0 = *(const float4*)(arow + kc * 32);
        float4 f1 = *(const float4*)(arow + kc * 32 + 4);
        a[0] = (_Float16)f0.x; a[1] = (_Float16)f0.y;
        a[2] = (_Float16)f0.z; a[3] = (_Float16)f0.w;
        a[4] = (_Float16)f1.x; a[5] = (_Float16)f1.y;
        a[6] = (_Float16)f1.z; a[7] = (_Float16)f1.w;
      } else {
        a = *(const half8*)(arow + kc * 32);
      }
#pragma unroll
      for (int nt = 0; nt < 4; nt++)
        acc[nt] = __builtin_amdgcn_mfma_f32_16x16x32_f16(a, bf[nt][kc], acc[nt], 0, 0, 0);
    }

    // attention scalars: reduce over the col group
    float ps[4], pd[4];
#pragma unroll
    for (int r = 0; r < 4; r++) { ps[r] = 0.f; pd[r] = 0.f; }
#pragma unroll
    for (int nt = 0; nt < 4; nt++)
#pragma unroll
      for (int r = 0; r < 4; r++) {
        ps[r] += acc[nt][r] * sa[nt];
        pd[r] += acc[nt][r] * sd[nt];
      }
#pragma unroll
    for (int r = 0; r < 4; r++)
#pragma unroll
      for (int m = 1; m < 16; m <<= 1) {
        ps[r] += __shfl_xor(ps[r], m);
        pd[r] += __shfl_xor(pd[r], m);
      }
    if (col == 0) {
#pragma unroll
      for (int r = 0; r < 4; r++) {
        int node = nb + quad * 4 + r;
        if (node < N) { as_[node] = ps[r]; ad_[node] = pd[r]; }
      }
    }

    // h store via wave-private LDS transpose (no barrier: same wave r/w)
#pragma unroll
    for (int nt = 0; nt < 4; nt++)
#pragma unroll
      for (int r = 0; r < 4; r++)
        sh[w][(quad * 4 + r) * 72 + nt * 16 + col] = (_Float16)acc[nt][r];
    int nr = lane >> 2, c4 = lane & 3;
    int node = nb + nr;
    if (node < N)
      store_row_fp8(&sh[w][nr * 72 + c4 * 16], h8 + (size_t)node * 64 + c4 * 16);
  }
}

// ---------------- LDS-staged agg inner loop (fp8 rows, unroll 4) ----------
// Block's 32 nodes own a contiguous CSR slice. Stage src indices + as_
// scores into LDS cooperatively; octet loop issues ONLY h-row gathers
// (8 B/lane, one 64B line per edge). Decode fp8 via hw cvt; math f32.
__device__ __forceinline__ void agg_block_stage(
    const uint2* __restrict__ h8v, const float* __restrict__ as_in,
    const int* __restrict__ csr_src, int* __restrict__ s_src,
    float* __restrict__ s_as, int t, int co,
    int e0, int eEnd, int rs, int re, float adn,
    float4& A0, float4& A1, float& den) {
  for (int cs = e0; cs < eEnd; cs += ECAP) {
    int ce = cs + ECAP; if (ce > eEnd) ce = eEnd;
    int cnt = ce - cs;
    __syncthreads();  // protect LDS reuse across chunks
    for (int i = t; i < cnt; i += 256) {
      int s = csr_src[cs + i];
      s_src[i] = s;
      s_as[i] = as_in[s];
    }
    __syncthreads();
    int a0 = rs > cs ? rs : cs;
    int a1 = re < ce ? re : ce;
    for (int s = a0; s < a1; s += 4) {
      int idx[4];
#pragma unroll
      for (int j = 0; j < 4; j++) {
        int sj = s + j;
        idx[j] = ((sj < a1) ? sj : (a1 - 1)) - cs;
      }
      uint2 hv[4];
#pragma unroll
      for (int j = 0; j < 4; j++) hv[j] = h8v[(size_t)s_src[idx[j]] * 8 + co];
      float cf[4];
#pragma unroll
      for (int j = 0; j < 4; j++) {
        float e = s_as[idx[j]] + adn;
        e = fmaxf(e, 0.2f * e);  // leaky_relu(0.2)
        cf[j] = (s + j < a1) ? __expf(e) : 0.f;
      }
#pragma unroll
      for (int j = 0; j < 4; j++) {
        v2f f0 = __builtin_amdgcn_cvt_pk_f32_fp8(hv[j].x, false);
        v2f f1 = __builtin_amdgcn_cvt_pk_f32_fp8(hv[j].x, true);
        v2f f2 = __builtin_amdgcn_cvt_pk_f32_fp8(hv[j].y, false);
        v2f f3 = __builtin_amdgcn_cvt_pk_f32_fp8(hv[j].y, true);
        float c = cf[j];
        den += c;
        A0.x += c * f0[0]; A0.y += c * f0[1]; A0.z += c * f1[0]; A0.w += c * f1[1];
        A1.x += c * f2[0]; A1.y += c * f2[1]; A1.z += c * f3[0]; A1.w += c * f3[1];
      }
    }
  }
}

// finish one node: normalize + bias + relu -> 8 fp16
__device__ __forceinline__ void agg_finish(const float4& A0, const float4& A1,
                                           float den, const float* __restrict__ bprev,
                                           int co, _Float16* o) {
  float inv = 1.0f / (den + 1e-16f);
  float4 b0 = *(const float4*)&bprev[co * 8];
  float4 b1 = *(const float4*)&bprev[co * 8 + 4];
  o[0] = (_Float16)fmaxf(A0.x * inv + b0.x, 0.f);
  o[1] = (_Float16)fmaxf(A0.y * inv + b0.y, 0.f);
  o[2] = (_Float16)fmaxf(A0.z * inv + b0.z, 0.f);
  o[3] = (_Float16)fmaxf(A0.w * inv + b0.w, 0.f);
  o[4] = (_Float16)fmaxf(A1.x * inv + b1.x, 0.f);
  o[5] = (_Float16)fmaxf(A1.y * inv + b1.y, 0.f);
  o[6] = (_Float16)fmaxf(A1.z * inv + b1.z, 0.f);
  o[7] = (_Float16)fmaxf(A1.w * inv + b1.w, 0.f);
}

// ---------------- fused agg (layer L) + lin (layer L+1) ----------------
// Block = 32 nodes = two 16-node MFMA tiles. Phase A0: stage edge slice in
// LDS. Phase A: 4 waves aggregate 8 nodes each into padded LDS tile (fp16).
// Phase B: waves 0,1 run the 16x64x64 MFMA; h8/as/ad written for next layer.
__global__ __launch_bounds__(256) void agg_lin_kernel(
    const uint2* __restrict__ h8in, const float* __restrict__ as_in,
    const float* __restrict__ ad_in, const int* __restrict__ csr_src,
    const int* __restrict__ row_start, const float* __restrict__ bprev,
    const float* __restrict__ W, const float* __restrict__ a_src,
    const float* __restrict__ a_dst, unsigned char* __restrict__ h8out,
    float* __restrict__ as_out, float* __restrict__ ad_out, int N) {
  __shared__ int s_src[ECAP];
  __shared__ float s_as[ECAP];
  __shared__ _Float16 shh[32][72];     // agg output tile (padded)
  __shared__ _Float16 sht[2][16 * 72]; // phase-B transpose (wave-private)
  const int t = threadIdx.x;
  const int lane = t & 63, w = t >> 6;
  const int base = blockIdx.x * 32;

  // ---- phase A: aggregate 32 nodes (1 per octet), edges staged in LDS ----
  {
    const int ng = lane >> 3, co = lane & 7;
    const int ln = w * 8 + ng;
    int n = base + ln;
    int nc = (n < N) ? n : (N - 1);  // clamp: redundant work, guarded stores
    int rs = row_start[nc], re = row_start[nc + 1];
    float adn = ad_in[nc];
    int nend = base + 32; if (nend > N) nend = N;
    int e0 = row_start[base], eEnd = row_start[nend];
    float4 A0 = make_float4(0.f, 0.f, 0.f, 0.f);
    float4 A1 = make_float4(0.f, 0.f, 0.f, 0.f);
    float den = 0.f;
    agg_block_stage(h8in, as_in, csr_src, s_src, s_as, t, co,
                    e0, eEnd, rs, re, adn, A0, A1, den);
    _Float16 o[8];
    agg_finish(A0, A1, den, bprev, co, o);
    *(float4*)&shh[ln][co * 8] = *(float4*)o;
  }
  __syncthreads();
  if (w >= 2) return;

  // ---- phase B: lin for tile w (16 nodes), wave-per-tile ----
  const int col = lane & 15, quad = lane >> 4;
  half8 bf[4][2];
  float sa[4], sd[4];
#pragma unroll
  for (int nt = 0; nt < 4; nt++) {
#pragma unroll
    for (int kc = 0; kc < 2; kc++) {
      half8 v;
#pragma unroll
      for (int j = 0; j < 8; j++)
        v[j] = (_Float16)W[(kc * 32 + quad * 8 + j) * 64 + nt * 16 + col];
      bf[nt][kc] = v;
    }
    sa[nt] = a_src[nt * 16 + col];
    sd[nt] = a_dst[nt * 16 + col];
  }

  const int nb = base + w * 16;
  v4f acc[4];
#pragma unroll
  for (int nt = 0; nt < 4; nt++) acc[nt] = (v4f){0.f, 0.f, 0.f, 0.f};
#pragma unroll
  for (int kc = 0; kc < 2; kc++) {
    half8 a = *(const half8*)&shh[w * 16 + col][kc * 32 + quad * 8];
#pragma unroll
    for (int nt = 0; nt < 4; nt++)
      acc[nt] = __builtin_amdgcn_mfma_f32_16x16x32_f16(a, bf[nt][kc], acc[nt], 0, 0, 0);
  }

  float ps[4], pd[4];
#pragma unroll
  for (int r = 0; r < 4; r++) { ps[r] = 0.f; pd[r] = 0.f; }
#pragma unroll
  for (int nt = 0; nt < 4; nt++)
#pragma unroll
    for (int r = 0; r < 4; r++) {
      ps[r] += acc[nt][r] * sa[nt];
      pd[r] += acc[nt][r] * sd[nt];
    }
#pragma unroll
  for (int r = 0; r < 4; r++)
#pragma unroll
    for (int m = 1; m < 16; m <<= 1) {
      ps[r] += __shfl_xor(ps[r], m);
      pd[r] += __shfl_xor(pd[r], m);
    }
  if (col == 0) {
#pragma unroll
    for (int r = 0; r < 4; r++) {
      int node = nb + quad * 4 + r;
      if (node < N) { as_out[node] = ps[r]; ad_out[node] = pd[r]; }
    }
  }

#pragma unroll
  for (int nt = 0; nt < 4; nt++)
#pragma unroll
    for (int r = 0; r < 4; r++)
      sht[w][(quad * 4 + r) * 72 + nt * 16 + col] = (_Float16)acc[nt][r];
  int nr = lane >> 2, c4 = lane & 3;
  int node = nb + nr;
  if (node < N)
    store_row_fp8(&sht[w][nr * 72 + c4 * 16], h8out + (size_t)node * 64 + c4 * 16);
}

// ---------------- fused agg (layer 3) + global max pool + root ----------------
__global__ __launch_bounds__(256) void agg_pool_kernel(
    const uint2* __restrict__ h8in, const float* __restrict__ as_in,
    const float* __restrict__ ad_in, const int* __restrict__ csr_src,
    const int* __restrict__ row_start, const float* __restrict__ bprev,
    const int* __restrict__ batch, float* __restrict__ pool,
    int* __restrict__ root, int N) {
  __shared__ int s_src[ECAP];
  __shared__ float s_as[ECAP];
  __shared__ float red[4][64];
  const int t = threadIdx.x;
  const int lane = t & 63, w = t >> 6;
  const int ng = lane >> 3, co = lane & 7;
  const int ln = w * 8 + ng;
  const int base = blockIdx.x * 32;
  int n = base + ln;
  int nc = (n < N) ? n : (N - 1);
  int rs = row_start[nc], re = row_start[nc + 1];
  float adn = ad_in[nc];
  int nend = base + 32; if (nend > N) nend = N;
  int e0 = row_start[base], eEnd = row_start[nend];
  float4 A0 = make_float4(0.f, 0.f, 0.f, 0.f);
  float4 A1 = make_float4(0.f, 0.f, 0.f, 0.f);
  float den = 0.f;
  agg_block_stage(h8in, as_in, csr_src, s_src, s_as, t, co,
                  e0, eEnd, rs, re, adn, A0, A1, den);
  // round through fp16 to keep parity with the fp16 handoff path
  _Float16 o[8];
  agg_finish(A0, A1, den, bprev, co, o);
  float ov[8];
#pragma unroll
  for (int j = 0; j < 8; j++) ov[j] = (float)o[j];

  int g = batch[nc];
  if (co == 0 && n < N) {
    if (n == 0 || batch[n - 1] != g) atomicMin(&root[g], n);
  }

  int bstart = base;
  int bend = base + 31; if (bend >= N) bend = N - 1;
  int gfirst = batch[bstart];
  int glast = batch[bend];
  if (gfirst == glast) {
    // block covers one graph: reduce 32 nodes -> 64ch, one atomic/ch.
    // clamped lanes replay node N-1 into its own graph's max: no-op.
#pragma unroll
    for (int m = 8; m < 64; m <<= 1)
#pragma unroll
      for (int j = 0; j < 8; j++) ov[j] = fmaxf(ov[j], __shfl_xor(ov[j], m));
    if (ng == 0)
#pragma unroll
      for (int j = 0; j < 8; j++) red[w][co * 8 + j] = ov[j];
    __syncthreads();
    if (t < 64) {
      float m0 = fmaxf(red[0][t], red[1][t]);
      float m1 = fmaxf(red[2][t], red[3][t]);
      atomicMax((int*)&pool[(size_t)gfirst * 64 + t], __float_as_int(fmaxf(m0, m1)));
    }
  } else {
    // graph boundary inside block (~G blocks total): per-lane atomics
#pragma unroll
    for (int j = 0; j < 8; j++)
      if (n < N) atomicMax((int*)&pool[(size_t)g * 64 + co * 8 + j], __float_as_int(ov[j]));
  }
}

// ---------------- final fused MLP head (wave per graph) ----------------
__global__ void final_kernel(const float* __restrict__ pool, const int* __restrict__ root,
                             const float* __restrict__ x,
                             const float* __restrict__ lin0_W, const float* __restrict__ lin0_b,
                             const float* __restrict__ linnews_W, const float* __restrict__ linnews_b,
                             const float* __restrict__ lin1_W, const float* __restrict__ lin1_b,
                             float* __restrict__ out, int G, int N) {
  int t = threadIdx.x;
  int lane = t & 63, w = t >> 6;
  int g = blockIdx.x * 4 + w;
  if (g >= G) return;
  float hp = 0.f;
  for (int k = 0; k < 64; k++) hp += pool[(size_t)g * 64 + k] * lin0_W[k * 64 + lane];
  hp = fmaxf(hp + lin0_b[lane], 0.f);
  int r = root[g]; if (r > N - 1) r = N - 1; if (r < 0) r = 0;
  float nw = 0.f;
  for (int k = 0; k < 128; k++) nw += x[(size_t)r * 128 + k] * linnews_W[k * 64 + lane];
  nw = fmaxf(nw + linnews_b[lane], 0.f);
  float p = hp * lin1_W[lane] + nw * lin1_W[64 + lane];
  for (int k = 1; k < 64; k <<= 1) p += __shfl_xor(p, k);
  if (lane == 0) out[g] = 1.0f / (1.0f + __expf(-(p + lin1_b[0])));
}

// ---------------- launch ----------------
extern "C" void kernel_launch(void* const* d_in, const int* in_sizes, int n_in,
                              void* d_out, int out_size, void* d_ws, size_t ws_size,
                              hipStream_t stream) {
  (void)n_in; (void)ws_size;
  const float* x      = (const float*)d_in[0];
  const int*   adj    = (const int*)d_in[1];
  const int*   batch  = (const int*)d_in[2];
  const float* W1     = (const float*)d_in[3];
  const float* asrc1  = (const float*)d_in[4];
  const float* adst1  = (const float*)d_in[5];
  const float* b1     = (const float*)d_in[6];
  const float* W2     = (const float*)d_in[7];
  const float* asrc2  = (const float*)d_in[8];
  const float* adst2  = (const float*)d_in[9];
  const float* b2     = (const float*)d_in[10];
  const float* W3     = (const float*)d_in[11];
  const float* asrc3  = (const float*)d_in[12];
  const float* adst3  = (const float*)d_in[13];
  const float* b3     = (const float*)d_in[14];
  const float* lnW    = (const float*)d_in[15];
  const float* lnb    = (const float*)d_in[16];
  const float* l0W    = (const float*)d_in[17];
  const float* l0b    = (const float*)d_in[18];
  const float* l1W    = (const float*)d_in[19];
  const float* l1b    = (const float*)d_in[20];
  float* outp = (float*)d_out;

  const int N = in_sizes[2];
  const int E = in_sizes[1] / 2;
  const int Etot = E + N;
  const int G = out_size;
  const int B = (N + 255) / 256;  // real buckets (<= BPAD)

  const int* src_e = adj;
  const int* dst_e = adj + E;

  uintptr_t p = (uintptr_t)d_ws;
  auto alloc = [&](size_t bytes) -> void* {
    void* r = (void*)p;
    p += (bytes + 255) & ~(size_t)255;
    return r;
  };
  int*      hist      = (int*)alloc((size_t)BPAD * NBLK * 4);
  int*      row_start = (int*)alloc((size_t)(N + 1) * 4);
  int*      csr_src   = (int*)alloc((size_t)Etot * 4);
  unsigned int* ebuf  = (unsigned int*)alloc((size_t)E * 4);
  unsigned char* hA   = (unsigned char*)alloc((size_t)N * 64);  // h ping (fp8)
  unsigned char* hB   = (unsigned char*)alloc((size_t)N * 64);  // h pong (fp8)
  float*    asA       = (float*)alloc((size_t)N * 4);
  float*    adA       = (float*)alloc((size_t)N * 4);
  float*    asB       = (float*)alloc((size_t)N * 4);
  float*    adB       = (float*)alloc((size_t)N * 4);
  float*    pool      = (float*)alloc((size_t)G * 64 * 4);
  int*      root      = (int*)alloc((size_t)G * 4);

  int chunk = (E + NBLK - 1) / NBLK;
  hist_kernel<<<dim3(NBLK), dim3(256), 0, stream>>>(dst_e, hist, E, chunk, pool, root, G);
  hscan_kernel<<<dim3(1), dim3(256), 0, stream>>>(hist);
  scatter_kernel<<<dim3(NBLK), dim3(256), 0, stream>>>(src_e, dst_e, hist, ebuf, E, chunk);
  build_kernel<<<dim3(B), dim3(256), 0, stream>>>(ebuf, hist, row_start, csr_src, N, E);

  const int aggGrid = (N + 31) / 32;
  const int nwaves = LINBLK * 4;

  // layer 1 lin (x fp32 -> h fp8, as, ad)
  lin_attn_kernel<128, float><<<dim3(LINBLK), dim3(256), 0, stream>>>(
      x, W1, asrc1, adst1, hA, asA, adA, N, nwaves);
  // agg1 + lin2 fused (ping -> pong)
  agg_lin_kernel<<<dim3(aggGrid), dim3(256), 0, stream>>>(
      (const uint2*)hA, asA, adA, csr_src, row_start, b1, W2, asrc2, adst2, hB, asB, adB, N);
  // agg2 + lin3 fused (pong -> ping)
  agg_lin_kernel<<<dim3(aggGrid), dim3(256), 0, stream>>>(
      (const uint2*)hB, asB, adB, csr_src, row_start, b2, W3, asrc3, adst3, hA, asA, adA, N);
  // agg3 + pool + root fused
  agg_pool_kernel<<<dim3(aggGrid), dim3(256), 0, stream>>>(
      (const uint2*)hA, asA, adA, csr_src, row_start, b3, batch, pool, root, N);

  // head
  final_kernel<<<dim3((G + 3) / 4), dim3(256), 0, stream>>>(
      pool, root, x, l0W, l0b, lnW, lnb, l1W, l1b, outp, G, N);
}

// Round 6
// 294.657 us; speedup vs baseline: 1.0502x; 1.0232x over previous
//
#include <hip/hip_runtime.h>
#include <hip/hip_fp16.h>
#include <cstdint>
#include <type_traits>

#define THREADS 256
#define NBLK 64     // blocks for hist/scatter
#define BPAD 512    // padded bucket count (dst>>8; N<=131072)
#define LINBLK 640  // blocks for lin_attn (layer 1)
#define ECAP 1024   // staged edges per chunk (32-node block; Poisson mean ~352)

typedef _Float16 half8 __attribute__((ext_vector_type(8)));
typedef float v4f __attribute__((ext_vector_type(4)));
typedef float v2f __attribute__((ext_vector_type(2)));

// ---------------- CSR build: bucket sort, no global atomics ----------------
// block 0 also zero-inits pool/root (used much later; no ordering hazard).
__global__ __launch_bounds__(256) void hist_kernel(const int* __restrict__ dst_e,
                                                   int* __restrict__ hist, int E, int chunk,
                                                   float* __restrict__ pool, int* __restrict__ root,
                                                   int G) {
  __shared__ int hcnt[BPAD];
  int t = threadIdx.x, blk = blockIdx.x;
  if (blk == 0) {
    for (int i = t; i < G * 64; i += 256) pool[i] = 0.0f;
    for (int i = t; i < G; i += 256) root[i] = 0x7fffffff;
  }
  for (int i = t; i < BPAD; i += 256) hcnt[i] = 0;
  __syncthreads();
  int s = blk * chunk, e = s + chunk;
  if (e > E) e = E;
  for (int i = s + t; i < e; i += 256) atomicAdd(&hcnt[dst_e[i] >> 8], 1);
  __syncthreads();
  for (int b = t; b < BPAD; b += 256) hist[b * NBLK + blk] = hcnt[b];
}

__global__ __launch_bounds__(256) void hscan_kernel(int* __restrict__ hist) {
  __shared__ int part[256];
  const int PER = (BPAD * NBLK) / 256;  // 128
  int t = threadIdx.x;
  int base = t * PER;
  int sum = 0;
  for (int k = 0; k < PER; k++) sum += hist[base + k];
  part[t] = sum;
  __syncthreads();
  int own = sum;
  for (int off = 1; off < 256; off <<= 1) {
    int v = (t >= off) ? part[t - off] : 0;
    __syncthreads();
    part[t] += v;
    __syncthreads();
  }
  int run = part[t] - own;
  for (int k = 0; k < PER; k++) {
    int h = hist[base + k];
    hist[base + k] = run;
    run += h;
  }
}

// scatter edges into bucket-partitioned ebuf, packed (src<<8)|(dst&255).
__global__ __launch_bounds__(256) void scatter_kernel(const int* __restrict__ src_e,
                                                      const int* __restrict__ dst_e,
                                                      const int* __restrict__ hist,
                                                      unsigned int* __restrict__ ebuf,
                                                      int E, int chunk) {
  __shared__ int cur[BPAD];
  int t = threadIdx.x, blk = blockIdx.x;
  for (int b = t; b < BPAD; b += 256) cur[b] = hist[b * NBLK + blk];
  __syncthreads();
  int s = blk * chunk, e = s + chunk;
  if (e > E) e = E;
  for (int i = s + t; i < e; i += 256) {
    int d = dst_e[i];
    unsigned int sv = (unsigned int)src_e[i];
    int slot = atomicAdd(&cur[d >> 8], 1);
    ebuf[slot] = (sv << 8) | (unsigned int)(d & 255);
  }
}

// per-bucket CSR finalize: row_start + csr_src (+self-loop in last slot).
__global__ __launch_bounds__(256) void build_kernel(const unsigned int* __restrict__ ebuf,
                                                    const int* __restrict__ hist,
                                                    int* __restrict__ row_start,
                                                    int* __restrict__ csr_src,
                                                    int N, int E) {
  __shared__ int counts[256];
  __shared__ int sc[256];
  __shared__ int curw[256];
  int t = threadIdx.x, b = blockIdx.x;
  int nbase = b * 256;
  int ebase = hist[b * NBLK];
  int eend = hist[(b + 1) * NBLK];
  counts[t] = 0;
  __syncthreads();
  int ecount = eend - ebase;
  for (int i = t; i < ecount; i += 256)
    atomicAdd(&counts[ebuf[ebase + i] & 255u], 1);
  __syncthreads();
  int n = nbase + t;
  int val = (n < N) ? counts[t] + 1 : 0;  // +1 self-loop
  sc[t] = val;
  __syncthreads();
  int own = val;
  for (int off = 1; off < 256; off <<= 1) {
    int v = (t >= off) ? sc[t - off] : 0;
    __syncthreads();
    sc[t] += v;
    __syncthreads();
  }
  int myloc = sc[t] - own;  // exclusive
  int rowb = ebase + nbase;  // prior real edges + prior self-loops
  if (n < N) {
    row_start[n] = rowb + myloc;
    csr_src[rowb + myloc + counts[t]] = n;  // self-loop in last slot
    if (n == N - 1) row_start[N] = rowb + myloc + counts[t] + 1;
  }
  curw[t] = rowb + myloc;
  __syncthreads();
  for (int i = t; i < ecount; i += 256) {
    unsigned int ev = ebuf[ebase + i];
    int pos = atomicAdd(&curw[ev & 255u], 1);
    csr_src[pos] = (int)(ev >> 8);
  }
}

// ---- fp8 row store: 16 fp16 (LDS transpose row segment) -> 16 fp8 e4m3 ----
// h's ONLY consumer is the agg gather; fp8 halves lines-per-edge (2 -> 1).
__device__ __forceinline__ void store_row_fp8(const _Float16* hp, unsigned char* dst) {
  unsigned int d[4];
#pragma unroll
  for (int q = 0; q < 4; q++) {
    float f0 = (float)hp[q * 4 + 0], f1 = (float)hp[q * 4 + 1];
    float f2 = (float)hp[q * 4 + 2], f3 = (float)hp[q * 4 + 3];
    unsigned int w0 = __builtin_amdgcn_cvt_pk_fp8_f32(f0, f1, 0, false);
    d[q] = __builtin_amdgcn_cvt_pk_fp8_f32(f2, f3, w0, true);
  }
  uint4 v; v.x = d[0]; v.y = d[1]; v.z = d[2]; v.w = d[3];
  *(uint4*)dst = v;
}

// ---------------- linear + attention scalars (MFMA), layer 1 ----------------
// h = in @ W via v_mfma_f32_16x16x32_f16. Layouts (m89/m91/m120):
//   A[m=lane&15][k=quad*8+j]; B[k=quad*8+j][n=lane&15];
//   D: row(m)=quad*4+reg, col(n)=lane&15.
// Transpose LDS padded to stride 72 halves: 2-way banks on vector reads.
// Output h stored fp8 e4m3 (64 B/row); attention scalars from exact f32 acc.
template <int K, typename TIN>
__global__ __launch_bounds__(256) void lin_attn_kernel(
    const TIN* __restrict__ in, const float* __restrict__ W,
    const float* __restrict__ a_src, const float* __restrict__ a_dst,
    unsigned char* __restrict__ h8, float* __restrict__ as_, float* __restrict__ ad_,
    int N, int nwaves) {
  constexpr int NKC = K / 32;
  __shared__ _Float16 sh[4][16 * 72];  // per-wave transpose buffer (padded)
  const int t = threadIdx.x;
  const int lane = t & 63, w = t >> 6;
  const int col = lane & 15, quad = lane >> 4;
  const int wid = blockIdx.x * 4 + w;

  // B fragments from W (fp32 -> fp16), reused across all tiles
  half8 bf[4][NKC];
#pragma unroll
  for (int nt = 0; nt < 4; nt++)
#pragma unroll
    for (int kc = 0; kc < NKC; kc++) {
      half8 v;
#pragma unroll
      for (int j = 0; j < 8; j++)
        v[j] = (_Float16)W[(kc * 32 + quad * 8 + j) * 64 + nt * 16 + col];
      bf[nt][kc] = v;
    }
  float sa[4], sd[4];
#pragma unroll
  for (int nt = 0; nt < 4; nt++) {
    sa[nt] = a_src[nt * 16 + col];
    sd[nt] = a_dst[nt * 16 + col];
  }

  const int ntiles = (N + 15) >> 4;
  for (int tile = wid; tile < ntiles; tile += nwaves) {
    const int nb = tile << 4;
    int nodeA = nb + col;
    if (nodeA >= N) nodeA = N - 1;
    const TIN* arow = in + (size_t)nodeA * K + quad * 8;

    v4f acc[4];
#pragma unroll
    for (int nt = 0; nt < 4; nt++) acc[nt] = (v4f){0.f, 0.f, 0.f, 0.f};

#pragma unroll
    for (int kc = 0; kc < NKC; kc++) {
      half8 a;
      if constexpr (std::is_same<TIN, float>::value) {
        float4 f0 = *(const float4*)(arow + kc * 32);
        float4 f1 = *(const float4*)(arow + kc * 32 + 4);
        a[0] = (_Float16)f0.x; a[1] = (_Float16)f0.y;
        a[2] = (_Float16)f0.z; a[3] = (_Float16)f0.w;
        a[4] = (_Float16)f1.x; a[5] = (_Float16)f1.y;
        a[6] = (_Float16)f1.z; a[7] = (_Float16)f1.w;
      } else {
        a = *(const half8*)(arow + kc * 32);
      }
#pragma unroll
      for (int nt = 0; nt < 4; nt++)
        acc[nt] = __builtin_amdgcn_mfma_f32_16x16x32_f16(a, bf[nt][kc], acc[nt], 0, 0, 0);
    }

    // attention scalars: reduce over the col group
    float ps[4], pd[4];
#pragma unroll
    for (int r = 0; r < 4; r++) { ps[r] = 0.f; pd[r] = 0.f; }
#pragma unroll
    for (int nt = 0; nt < 4; nt++)
#pragma unroll
      for (int r = 0; r < 4; r++) {
        ps[r] += acc[nt][r] * sa[nt];
        pd[r] += acc[nt][r] * sd[nt];
      }
#pragma unroll
    for (int r = 0; r < 4; r++)
#pragma unroll
      for (int m = 1; m < 16; m <<= 1) {
        ps[r] += __shfl_xor(ps[r], m);
        pd[r] += __shfl_xor(pd[r], m);
      }
    if (col == 0) {
#pragma unroll
      for (int r = 0; r < 4; r++) {
        int node = nb + quad * 4 + r;
        if (node < N) { as_[node] = ps[r]; ad_[node] = pd[r]; }
      }
    }

    // h store via wave-private LDS transpose (no barrier: same wave r/w)
#pragma unroll
    for (int nt = 0; nt < 4; nt++)
#pragma unroll
      for (int r = 0; r < 4; r++)
        sh[w][(quad * 4 + r) * 72 + nt * 16 + col] = (_Float16)acc[nt][r];
    int nr = lane >> 2, c4 = lane & 3;
    int node = nb + nr;
    if (node < N)
      store_row_fp8(&sh[w][nr * 72 + c4 * 16], h8 + (size_t)node * 64 + c4 * 16);
  }
}

// ---------------- LDS-staged agg inner loop (fp8 rows, 2-stage pipeline) ----
// Block's 32 nodes own a contiguous CSR slice. Stage src indices + as_
// scores into LDS (2-way unrolled: both csr loads issued before the two
// dependent as_ gathers). Octet loop prefetches the NEXT batch's 4 h-row
// gathers before consuming the current batch: consumption waits at
// vmcnt(4) instead of vmcnt(0), hiding gather latency under VALU work.
// Prefetch state is uint2[4] = 8 VGPR (fp8 rows make this affordable).
__device__ __forceinline__ void agg_block_stage(
    const uint2* __restrict__ h8v, const float* __restrict__ as_in,
    const int* __restrict__ csr_src, int* __restrict__ s_src,
    float* __restrict__ s_as, int t, int co,
    int e0, int eEnd, int rs, int re, float adn,
    float4& A0, float4& A1, float& den) {
  bool first = true;
  for (int cs = e0; cs < eEnd; cs += ECAP) {
    int ce = cs + ECAP; if (ce > eEnd) ce = eEnd;
    int cnt = ce - cs;
    if (!first) __syncthreads();  // protect LDS reuse across chunks
    first = false;
    for (int i = t; i < cnt; i += 512) {
      int s0 = csr_src[cs + i];
      bool has2 = (i + 256 < cnt);
      int s1 = has2 ? csr_src[cs + i + 256] : s0;
      float av0 = as_in[s0];
      float av1 = as_in[s1];
      s_src[i] = s0; s_as[i] = av0;
      if (has2) { s_src[i + 256] = s1; s_as[i + 256] = av1; }
    }
    __syncthreads();
    int a0 = rs > cs ? rs : cs;
    int a1 = re < ce ? re : ce;
    if (a0 >= a1) continue;  // barriers stay uniform (same dynamic count)

    auto loadhv = [&](int sb, uint2* hv) {
#pragma unroll
      for (int j = 0; j < 4; j++) {
        int sj = sb + j;
        int ii = ((sj < a1) ? sj : (a1 - 1)) - cs;
        hv[j] = h8v[(size_t)s_src[ii] * 8 + co];
      }
    };
    auto consume = [&](int sb, const uint2* hv) {
#pragma unroll
      for (int j = 0; j < 4; j++) {
        int sj = sb + j;
        int ii = ((sj < a1) ? sj : (a1 - 1)) - cs;
        float e = s_as[ii] + adn;
        e = fmaxf(e, 0.2f * e);  // leaky_relu(0.2)
        float c = (sj < a1) ? __expf(e) : 0.f;
        v2f f0 = __builtin_amdgcn_cvt_pk_f32_fp8(hv[j].x, false);
        v2f f1 = __builtin_amdgcn_cvt_pk_f32_fp8(hv[j].x, true);
        v2f f2 = __builtin_amdgcn_cvt_pk_f32_fp8(hv[j].y, false);
        v2f f3 = __builtin_amdgcn_cvt_pk_f32_fp8(hv[j].y, true);
        den += c;
        A0.x += c * f0[0]; A0.y += c * f0[1]; A0.z += c * f1[0]; A0.w += c * f1[1];
        A1.x += c * f2[0]; A1.y += c * f2[1]; A1.z += c * f3[0]; A1.w += c * f3[1];
      }
    };

    uint2 hvA[4];
    int s = a0;
    loadhv(s, hvA);
    for (s = a0 + 4; s < a1; s += 4) {
      uint2 hvB[4];
      loadhv(s, hvB);       // issue next batch before consuming current
      consume(s - 4, hvA);
#pragma unroll
      for (int j = 0; j < 4; j++) hvA[j] = hvB[j];
    }
    consume(s - 4, hvA);
  }
}

// finish one node: normalize + bias + relu -> 8 fp16
__device__ __forceinline__ void agg_finish(const float4& A0, const float4& A1,
                                           float den, const float* __restrict__ bprev,
                                           int co, _Float16* o) {
  float inv = 1.0f / (den + 1e-16f);
  float4 b0 = *(const float4*)&bprev[co * 8];
  float4 b1 = *(const float4*)&bprev[co * 8 + 4];
  o[0] = (_Float16)fmaxf(A0.x * inv + b0.x, 0.f);
  o[1] = (_Float16)fmaxf(A0.y * inv + b0.y, 0.f);
  o[2] = (_Float16)fmaxf(A0.z * inv + b0.z, 0.f);
  o[3] = (_Float16)fmaxf(A0.w * inv + b0.w, 0.f);
  o[4] = (_Float16)fmaxf(A1.x * inv + b1.x, 0.f);
  o[5] = (_Float16)fmaxf(A1.y * inv + b1.y, 0.f);
  o[6] = (_Float16)fmaxf(A1.z * inv + b1.z, 0.f);
  o[7] = (_Float16)fmaxf(A1.w * inv + b1.w, 0.f);
}

// ---------------- fused agg (layer L) + lin (layer L+1) ----------------
// Block = 32 nodes = two 16-node MFMA tiles. Phase A0: stage edge slice in
// LDS. Phase A: 4 waves aggregate 8 nodes each into padded LDS tile (fp16).
// Phase B: waves 0,1 run the 16x64x64 MFMA; h8/as/ad written for next layer.
__global__ __launch_bounds__(256) void agg_lin_kernel(
    const uint2* __restrict__ h8in, const float* __restrict__ as_in,
    const float* __restrict__ ad_in, const int* __restrict__ csr_src,
    const int* __restrict__ row_start, const float* __restrict__ bprev,
    const float* __restrict__ W, const float* __restrict__ a_src,
    const float* __restrict__ a_dst, unsigned char* __restrict__ h8out,
    float* __restrict__ as_out, float* __restrict__ ad_out, int N) {
  __shared__ int s_src[ECAP];
  __shared__ float s_as[ECAP];
  __shared__ _Float16 shh[32][72];     // agg output tile (padded)
  __shared__ _Float16 sht[2][16 * 72]; // phase-B transpose (wave-private)
  const int t = threadIdx.x;
  const int lane = t & 63, w = t >> 6;
  const int base = blockIdx.x * 32;

  // ---- phase A: aggregate 32 nodes (1 per octet), edges staged in LDS ----
  {
    const int ng = lane >> 3, co = lane & 7;
    const int ln = w * 8 + ng;
    int n = base + ln;
    int nc = (n < N) ? n : (N - 1);  // clamp: redundant work, guarded stores
    int rs = row_start[nc], re = row_start[nc + 1];
    float adn = ad_in[nc];
    int nend = base + 32; if (nend > N) nend = N;
    int e0 = row_start[base], eEnd = row_start[nend];
    float4 A0 = make_float4(0.f, 0.f, 0.f, 0.f);
    float4 A1 = make_float4(0.f, 0.f, 0.f, 0.f);
    float den = 0.f;
    agg_block_stage(h8in, as_in, csr_src, s_src, s_as, t, co,
                    e0, eEnd, rs, re, adn, A0, A1, den);
    _Float16 o[8];
    agg_finish(A0, A1, den, bprev, co, o);
    *(float4*)&shh[ln][co * 8] = *(float4*)o;
  }
  __syncthreads();
  if (w >= 2) return;

  // ---- phase B: lin for tile w (16 nodes), wave-per-tile ----
  const int col = lane & 15, quad = lane >> 4;
  half8 bf[4][2];
  float sa[4], sd[4];
#pragma unroll
  for (int nt = 0; nt < 4; nt++) {
#pragma unroll
    for (int kc = 0; kc < 2; kc++) {
      half8 v;
#pragma unroll
      for (int j = 0; j < 8; j++)
        v[j] = (_Float16)W[(kc * 32 + quad * 8 + j) * 64 + nt * 16 + col];
      bf[nt][kc] = v;
    }
    sa[nt] = a_src[nt * 16 + col];
    sd[nt] = a_dst[nt * 16 + col];
  }

  const int nb = base + w * 16;
  v4f acc[4];
#pragma unroll
  for (int nt = 0; nt < 4; nt++) acc[nt] = (v4f){0.f, 0.f, 0.f, 0.f};
#pragma unroll
  for (int kc = 0; kc < 2; kc++) {
    half8 a = *(const half8*)&shh[w * 16 + col][kc * 32 + quad * 8];
#pragma unroll
    for (int nt = 0; nt < 4; nt++)
      acc[nt] = __builtin_amdgcn_mfma_f32_16x16x32_f16(a, bf[nt][kc], acc[nt], 0, 0, 0);
  }

  float ps[4], pd[4];
#pragma unroll
  for (int r = 0; r < 4; r++) { ps[r] = 0.f; pd[r] = 0.f; }
#pragma unroll
  for (int nt = 0; nt < 4; nt++)
#pragma unroll
    for (int r = 0; r < 4; r++) {
      ps[r] += acc[nt][r] * sa[nt];
      pd[r] += acc[nt][r] * sd[nt];
    }
#pragma unroll
  for (int r = 0; r < 4; r++)
#pragma unroll
    for (int m = 1; m < 16; m <<= 1) {
      ps[r] += __shfl_xor(ps[r], m);
      pd[r] += __shfl_xor(pd[r], m);
    }
  if (col == 0) {
#pragma unroll
    for (int r = 0; r < 4; r++) {
      int node = nb + quad * 4 + r;
      if (node < N) { as_out[node] = ps[r]; ad_out[node] = pd[r]; }
    }
  }

#pragma unroll
  for (int nt = 0; nt < 4; nt++)
#pragma unroll
    for (int r = 0; r < 4; r++)
      sht[w][(quad * 4 + r) * 72 + nt * 16 + col] = (_Float16)acc[nt][r];
  int nr = lane >> 2, c4 = lane & 3;
  int node = nb + nr;
  if (node < N)
    store_row_fp8(&sht[w][nr * 72 + c4 * 16], h8out + (size_t)node * 64 + c4 * 16);
}

// ---------------- fused agg (layer 3) + global max pool + root ----------------
__global__ __launch_bounds__(256) void agg_pool_kernel(
    const uint2* __restrict__ h8in, const float* __restrict__ as_in,
    const float* __restrict__ ad_in, const int* __restrict__ csr_src,
    const int* __restrict__ row_start, const float* __restrict__ bprev,
    const int* __restrict__ batch, float* __restrict__ pool,
    int* __restrict__ root, int N) {
  __shared__ int s_src[ECAP];
  __shared__ float s_as[ECAP];
  __shared__ float red[4][64];
  const int t = threadIdx.x;
  const int lane = t & 63, w = t >> 6;
  const int ng = lane >> 3, co = lane & 7;
  const int ln = w * 8 + ng;
  const int base = blockIdx.x * 32;
  int n = base + ln;
  int nc = (n < N) ? n : (N - 1);
  int rs = row_start[nc], re = row_start[nc + 1];
  float adn = ad_in[nc];
  int nend = base + 32; if (nend > N) nend = N;
  int e0 = row_start[base], eEnd = row_start[nend];
  float4 A0 = make_float4(0.f, 0.f, 0.f, 0.f);
  float4 A1 = make_float4(0.f, 0.f, 0.f, 0.f);
  float den = 0.f;
  agg_block_stage(h8in, as_in, csr_src, s_src, s_as, t, co,
                  e0, eEnd, rs, re, adn, A0, A1, den);
  // round through fp16 to keep parity with the fp16 handoff path
  _Float16 o[8];
  agg_finish(A0, A1, den, bprev, co, o);
  float ov[8];
#pragma unroll
  for (int j = 0; j < 8; j++) ov[j] = (float)o[j];

  int g = batch[nc];
  if (co == 0 && n < N) {
    if (n == 0 || batch[n - 1] != g) atomicMin(&root[g], n);
  }

  int bstart = base;
  int bend = base + 31; if (bend >= N) bend = N - 1;
  int gfirst = batch[bstart];
  int glast = batch[bend];
  if (gfirst == glast) {
    // block covers one graph: reduce 32 nodes -> 64ch, one atomic/ch.
    // clamped lanes replay node N-1 into its own graph's max: no-op.
#pragma unroll
    for (int m = 8; m < 64; m <<= 1)
#pragma unroll
      for (int j = 0; j < 8; j++) ov[j] = fmaxf(ov[j], __shfl_xor(ov[j], m));
    if (ng == 0)
#pragma unroll
      for (int j = 0; j < 8; j++) red[w][co * 8 + j] = ov[j];
    __syncthreads();
    if (t < 64) {
      float m0 = fmaxf(red[0][t], red[1][t]);
      float m1 = fmaxf(red[2][t], red[3][t]);
      atomicMax((int*)&pool[(size_t)gfirst * 64 + t], __float_as_int(fmaxf(m0, m1)));
    }
  } else {
    // graph boundary inside block (~G blocks total): per-lane atomics
#pragma unroll
    for (int j = 0; j < 8; j++)
      if (n < N) atomicMax((int*)&pool[(size_t)g * 64 + co * 8 + j], __float_as_int(ov[j]));
  }
}

// ---------------- final fused MLP head (wave per graph) ----------------
__global__ void final_kernel(const float* __restrict__ pool, const int* __restrict__ root,
                             const float* __restrict__ x,
                             const float* __restrict__ lin0_W, const float* __restrict__ lin0_b,
                             const float* __restrict__ linnews_W, const float* __restrict__ linnews_b,
                             const float* __restrict__ lin1_W, const float* __restrict__ lin1_b,
                             float* __restrict__ out, int G, int N) {
  int t = threadIdx.x;
  int lane = t & 63, w = t >> 6;
  int g = blockIdx.x * 4 + w;
  if (g >= G) return;
  float hp = 0.f;
  for (int k = 0; k < 64; k++) hp += pool[(size_t)g * 64 + k] * lin0_W[k * 64 + lane];
  hp = fmaxf(hp + lin0_b[lane], 0.f);
  int r = root[g]; if (r > N - 1) r = N - 1; if (r < 0) r = 0;
  float nw = 0.f;
  for (int k = 0; k < 128; k++) nw += x[(size_t)r * 128 + k] * linnews_W[k * 64 + lane];
  nw = fmaxf(nw + linnews_b[lane], 0.f);
  float p = hp * lin1_W[lane] + nw * lin1_W[64 + lane];
  for (int k = 1; k < 64; k <<= 1) p += __shfl_xor(p, k);
  if (lane == 0) out[g] = 1.0f / (1.0f + __expf(-(p + lin1_b[0])));
}

// ---------------- launch ----------------
extern "C" void kernel_launch(void* const* d_in, const int* in_sizes, int n_in,
                              void* d_out, int out_size, void* d_ws, size_t ws_size,
                              hipStream_t stream) {
  (void)n_in; (void)ws_size;
  const float* x      = (const float*)d_in[0];
  const int*   adj    = (const int*)d_in[1];
  const int*   batch  = (const int*)d_in[2];
  const float* W1     = (const float*)d_in[3];
  const float* asrc1  = (const float*)d_in[4];
  const float* adst1  = (const float*)d_in[5];
  const float* b1     = (const float*)d_in[6];
  const float* W2     = (const float*)d_in[7];
  const float* asrc2  = (const float*)d_in[8];
  const float* adst2  = (const float*)d_in[9];
  const float* b2     = (const float*)d_in[10];
  const float* W3     = (const float*)d_in[11];
  const float* asrc3  = (const float*)d_in[12];
  const float* adst3  = (const float*)d_in[13];
  const float* b3     = (const float*)d_in[14];
  const float* lnW    = (const float*)d_in[15];
  const float* lnb    = (const float*)d_in[16];
  const float* l0W    = (const float*)d_in[17];
  const float* l0b    = (const float*)d_in[18];
  const float* l1W    = (const float*)d_in[19];
  const float* l1b    = (const float*)d_in[20];
  float* outp = (float*)d_out;

  const int N = in_sizes[2];
  const int E = in_sizes[1] / 2;
  const int Etot = E + N;
  const int G = out_size;
  const int B = (N + 255) / 256;  // real buckets (<= BPAD)

  const int* src_e = adj;
  const int* dst_e = adj + E;

  uintptr_t p = (uintptr_t)d_ws;
  auto alloc = [&](size_t bytes) -> void* {
    void* r = (void*)p;
    p += (bytes + 255) & ~(size_t)255;
    return r;
  };
  int*      hist      = (int*)alloc((size_t)BPAD * NBLK * 4);
  int*      row_start = (int*)alloc((size_t)(N + 1) * 4);
  int*      csr_src   = (int*)alloc((size_t)Etot * 4);
  unsigned int* ebuf  = (unsigned int*)alloc((size_t)E * 4);
  unsigned char* hA   = (unsigned char*)alloc((size_t)N * 64);  // h ping (fp8)
  unsigned char* hB   = (unsigned char*)alloc((size_t)N * 64);  // h pong (fp8)
  float*    asA       = (float*)alloc((size_t)N * 4);
  float*    adA       = (float*)alloc((size_t)N * 4);
  float*    asB       = (float*)alloc((size_t)N * 4);
  float*    adB       = (float*)alloc((size_t)N * 4);
  float*    pool      = (float*)alloc((size_t)G * 64 * 4);
  int*      root      = (int*)alloc((size_t)G * 4);

  int chunk = (E + NBLK - 1) / NBLK;
  hist_kernel<<<dim3(NBLK), dim3(256), 0, stream>>>(dst_e, hist, E, chunk, pool, root, G);
  hscan_kernel<<<dim3(1), dim3(256), 0, stream>>>(hist);
  scatter_kernel<<<dim3(NBLK), dim3(256), 0, stream>>>(src_e, dst_e, hist, ebuf, E, chunk);
  build_kernel<<<dim3(B), dim3(256), 0, stream>>>(ebuf, hist, row_start, csr_src, N, E);

  const int aggGrid = (N + 31) / 32;
  const int nwaves = LINBLK * 4;

  // layer 1 lin (x fp32 -> h fp8, as, ad)
  lin_attn_kernel<128, float><<<dim3(LINBLK), dim3(256), 0, stream>>>(
      x, W1, asrc1, adst1, hA, asA, adA, N, nwaves);
  // agg1 + lin2 fused (ping -> pong)
  agg_lin_kernel<<<dim3(aggGrid), dim3(256), 0, stream>>>(
      (const uint2*)hA, asA, adA, csr_src, row_start, b1, W2, asrc2, adst2, hB, asB, adB, N);
  // agg2 + lin3 fused (pong -> ping)
  agg_lin_kernel<<<dim3(aggGrid), dim3(256), 0, stream>>>(
      (const uint2*)hB, asB, adB, csr_src, row_start, b2, W3, asrc3, adst3, hA, asA, adA, N);
  // agg3 + pool + root fused
  agg_pool_kernel<<<dim3(aggGrid), dim3(256), 0, stream>>>(
      (const uint2*)hA, asA, adA, csr_src, row_start, b3, batch, pool, root, N);

  // head
  final_kernel<<<dim3((G + 3) / 4), dim3(256), 0, stream>>>(
      pool, root, x, l0W, l0b, lnW, lnb, l1W, l1b, outp, G, N);
}

// Round 7
// 290.185 us; speedup vs baseline: 1.0664x; 1.0154x over previous
//
#include <hip/hip_runtime.h>
#include <hip/hip_fp16.h>
#include <cstdint>
#include <type_traits>

#define THREADS 256
#define NBLK 64     // blocks for hist/scatter
#define BPAD 512    // padded bucket count (dst>>8; N<=131072)
#define ECAP 1024   // staged edges per chunk (32-node block; Poisson mean ~352)
#define LINB 392    // lin1 backfill blocks fused into each CSR stage

typedef _Float16 half8 __attribute__((ext_vector_type(8)));
typedef float v4f __attribute__((ext_vector_type(4)));
typedef float v2f __attribute__((ext_vector_type(2)));

// ---- fp8 row store: 16 fp16 (LDS transpose row segment) -> 16 fp8 e4m3 ----
// h's ONLY consumer is the agg gather; fp8 halves lines-per-edge (2 -> 1).
__device__ __forceinline__ void store_row_fp8(const _Float16* hp, unsigned char* dst) {
  unsigned int d[4];
#pragma unroll
  for (int q = 0; q < 4; q++) {
    float f0 = (float)hp[q * 4 + 0], f1 = (float)hp[q * 4 + 1];
    float f2 = (float)hp[q * 4 + 2], f3 = (float)hp[q * 4 + 3];
    unsigned int w0 = __builtin_amdgcn_cvt_pk_fp8_f32(f0, f1, 0, false);
    d[q] = __builtin_amdgcn_cvt_pk_fp8_f32(f2, f3, w0, true);
  }
  uint4 v; v.x = d[0]; v.y = d[1]; v.z = d[2]; v.w = d[3];
  *(uint4*)dst = v;
}

// ---------------- lin1 (x fp32 @ W1 -> h fp8 + attention scalars) -----------
// Persistent-wave tile loop over [tile0, tile1). MFMA 16x16x32_f16 layouts
// (m89/m91/m120): A[m=lane&15][k=quad*8+j]; B[k][n=lane&15];
// D: row=quad*4+reg, col=lane&15. Wave-private LDS transpose (stride 72).
// Fused as backfill blocks into the CSR-build chain (independent work).
__device__ __forceinline__ void lin1_run(
    const float* __restrict__ in, const float* __restrict__ W,
    const float* __restrict__ a_src, const float* __restrict__ a_dst,
    unsigned char* __restrict__ h8, float* __restrict__ as_, float* __restrict__ ad_,
    int N, int tile0, int tile1, int wid, int nwaves, _Float16* shw) {
  const int lane = threadIdx.x & 63;
  const int col = lane & 15, quad = lane >> 4;

  half8 bf[4][4];
#pragma unroll
  for (int nt = 0; nt < 4; nt++)
#pragma unroll
    for (int kc = 0; kc < 4; kc++) {
      half8 v;
#pragma unroll
      for (int j = 0; j < 8; j++)
        v[j] = (_Float16)W[(kc * 32 + quad * 8 + j) * 64 + nt * 16 + col];
      bf[nt][kc] = v;
    }
  float sa[4], sd[4];
#pragma unroll
  for (int nt = 0; nt < 4; nt++) {
    sa[nt] = a_src[nt * 16 + col];
    sd[nt] = a_dst[nt * 16 + col];
  }

  for (int tile = tile0 + wid; tile < tile1; tile += nwaves) {
    const int nb = tile << 4;
    int nodeA = nb + col;
    if (nodeA >= N) nodeA = N - 1;
    const float* arow = in + (size_t)nodeA * 128 + quad * 8;

    v4f acc[4];
#pragma unroll
    for (int nt = 0; nt < 4; nt++) acc[nt] = (v4f){0.f, 0.f, 0.f, 0.f};

#pragma unroll
    for (int kc = 0; kc < 4; kc++) {
      float4 f0 = *(const float4*)(arow + kc * 32);
      float4 f1 = *(const float4*)(arow + kc * 32 + 4);
      half8 a;
      a[0] = (_Float16)f0.x; a[1] = (_Float16)f0.y;
      a[2] = (_Float16)f0.z; a[3] = (_Float16)f0.w;
      a[4] = (_Float16)f1.x; a[5] = (_Float16)f1.y;
      a[6] = (_Float16)f1.z; a[7] = (_Float16)f1.w;
#pragma unroll
      for (int nt = 0; nt < 4; nt++)
        acc[nt] = __builtin_amdgcn_mfma_f32_16x16x32_f16(a, bf[nt][kc], acc[nt], 0, 0, 0);
    }

    // attention scalars: reduce over the col group
    float ps[4], pd[4];
#pragma unroll
    for (int r = 0; r < 4; r++) { ps[r] = 0.f; pd[r] = 0.f; }
#pragma unroll
    for (int nt = 0; nt < 4; nt++)
#pragma unroll
      for (int r = 0; r < 4; r++) {
        ps[r] += acc[nt][r] * sa[nt];
        pd[r] += acc[nt][r] * sd[nt];
      }
#pragma unroll
    for (int r = 0; r < 4; r++)
#pragma unroll
      for (int m = 1; m < 16; m <<= 1) {
        ps[r] += __shfl_xor(ps[r], m);
        pd[r] += __shfl_xor(pd[r], m);
      }
    if (col == 0) {
#pragma unroll
      for (int r = 0; r < 4; r++) {
        int node = nb + quad * 4 + r;
        if (node < N) { as_[node] = ps[r]; ad_[node] = pd[r]; }
      }
    }

    // h store via wave-private LDS transpose (no barrier: same wave r/w)
#pragma unroll
    for (int nt = 0; nt < 4; nt++)
#pragma unroll
      for (int r = 0; r < 4; r++)
        shw[(quad * 4 + r) * 72 + nt * 16 + col] = (_Float16)acc[nt][r];
    int nr = lane >> 2, c4 = lane & 3;
    int node = nb + nr;
    if (node < N)
      store_row_fp8(&shw[nr * 72 + c4 * 16], h8 + (size_t)node * 64 + c4 * 16);
  }
}

#define LIN_ARGS const float* __restrict__ x, const float* __restrict__ W1, \
                 const float* __restrict__ a1s, const float* __restrict__ a1d, \
                 unsigned char* __restrict__ h8, float* __restrict__ lin_as, \
                 float* __restrict__ lin_ad, int Nn, int tile0, int tile1, int nlw

// ---------------- CSR build chain, each stage hosting a lin1 slice ----------
// block 0 of hist also zero-inits pool/root (used much later; no hazard).
__global__ __launch_bounds__(256) void hist_lin_kernel(
    const int* __restrict__ dst_e, int* __restrict__ hist, int E, int chunk,
    float* __restrict__ pool, int* __restrict__ root, int G, LIN_ARGS) {
  __shared__ int hcnt[BPAD];
  __shared__ _Float16 sh[4][16 * 72];
  int t = threadIdx.x, blk = blockIdx.x;
  if (blk >= NBLK) {
    int wid = (blk - NBLK) * 4 + (t >> 6);
    lin1_run(x, W1, a1s, a1d, h8, lin_as, lin_ad, Nn, tile0, tile1, wid, nlw, sh[t >> 6]);
    return;
  }
  if (blk == 0) {
    for (int i = t; i < G * 64; i += 256) pool[i] = 0.0f;
    for (int i = t; i < G; i += 256) root[i] = 0x7fffffff;
  }
  for (int i = t; i < BPAD; i += 256) hcnt[i] = 0;
  __syncthreads();
  int s = blk * chunk, e = s + chunk;
  if (e > E) e = E;
  for (int i = s + t; i < e; i += 256) atomicAdd(&hcnt[dst_e[i] >> 8], 1);
  __syncthreads();
  for (int b = t; b < BPAD; b += 256) hist[b * NBLK + blk] = hcnt[b];
}

__global__ __launch_bounds__(256) void hscan_lin_kernel(int* __restrict__ hist, LIN_ARGS) {
  __shared__ int part[256];
  __shared__ _Float16 sh[4][16 * 72];
  int t = threadIdx.x, blk = blockIdx.x;
  if (blk >= 1) {
    int wid = (blk - 1) * 4 + (t >> 6);
    lin1_run(x, W1, a1s, a1d, h8, lin_as, lin_ad, Nn, tile0, tile1, wid, nlw, sh[t >> 6]);
    return;
  }
  const int PER = (BPAD * NBLK) / 256;  // 128
  int base = t * PER;
  int sum = 0;
  for (int k = 0; k < PER; k++) sum += hist[base + k];
  part[t] = sum;
  __syncthreads();
  int own = sum;
  for (int off = 1; off < 256; off <<= 1) {
    int v = (t >= off) ? part[t - off] : 0;
    __syncthreads();
    part[t] += v;
    __syncthreads();
  }
  int run = part[t] - own;
  for (int k = 0; k < PER; k++) {
    int h = hist[base + k];
    hist[base + k] = run;
    run += h;
  }
}

// scatter edges into bucket-partitioned ebuf, packed (src<<8)|(dst&255).
__global__ __launch_bounds__(256) void scatter_lin_kernel(
    const int* __restrict__ src_e, const int* __restrict__ dst_e,
    const int* __restrict__ hist, unsigned int* __restrict__ ebuf,
    int E, int chunk, LIN_ARGS) {
  __shared__ int cur[BPAD];
  __shared__ _Float16 sh[4][16 * 72];
  int t = threadIdx.x, blk = blockIdx.x;
  if (blk >= NBLK) {
    int wid = (blk - NBLK) * 4 + (t >> 6);
    lin1_run(x, W1, a1s, a1d, h8, lin_as, lin_ad, Nn, tile0, tile1, wid, nlw, sh[t >> 6]);
    return;
  }
  for (int b = t; b < BPAD; b += 256) cur[b] = hist[b * NBLK + blk];
  __syncthreads();
  int s = blk * chunk, e = s + chunk;
  if (e > E) e = E;
  for (int i = s + t; i < e; i += 256) {
    int d = dst_e[i];
    unsigned int sv = (unsigned int)src_e[i];
    int slot = atomicAdd(&cur[d >> 8], 1);
    ebuf[slot] = (sv << 8) | (unsigned int)(d & 255);
  }
}

// per-bucket CSR finalize: row_start + csr_src (+self-loop in last slot).
__global__ __launch_bounds__(256) void build_lin_kernel(
    const unsigned int* __restrict__ ebuf, const int* __restrict__ hist,
    int* __restrict__ row_start, int* __restrict__ csr_src,
    int N, int E, int BB, LIN_ARGS) {
  __shared__ int counts[256];
  __shared__ int sc[256];
  __shared__ int curw[256];
  __shared__ _Float16 sh[4][16 * 72];
  int t = threadIdx.x, b = blockIdx.x;
  if (b >= BB) {
    int wid = (b - BB) * 4 + (t >> 6);
    lin1_run(x, W1, a1s, a1d, h8, lin_as, lin_ad, Nn, tile0, tile1, wid, nlw, sh[t >> 6]);
    return;
  }
  int nbase = b * 256;
  int ebase = hist[b * NBLK];
  int eend = hist[(b + 1) * NBLK];
  counts[t] = 0;
  __syncthreads();
  int ecount = eend - ebase;
  for (int i = t; i < ecount; i += 256)
    atomicAdd(&counts[ebuf[ebase + i] & 255u], 1);
  __syncthreads();
  int n = nbase + t;
  int val = (n < N) ? counts[t] + 1 : 0;  // +1 self-loop
  sc[t] = val;
  __syncthreads();
  int own = val;
  for (int off = 1; off < 256; off <<= 1) {
    int v = (t >= off) ? sc[t - off] : 0;
    __syncthreads();
    sc[t] += v;
    __syncthreads();
  }
  int myloc = sc[t] - own;  // exclusive
  int rowb = ebase + nbase;  // prior real edges + prior self-loops
  if (n < N) {
    row_start[n] = rowb + myloc;
    csr_src[rowb + myloc + counts[t]] = n;  // self-loop in last slot
    if (n == N - 1) row_start[N] = rowb + myloc + counts[t] + 1;
  }
  curw[t] = rowb + myloc;
  __syncthreads();
  for (int i = t; i < ecount; i += 256) {
    unsigned int ev = ebuf[ebase + i];
    int pos = atomicAdd(&curw[ev & 255u], 1);
    csr_src[pos] = (int)(ev >> 8);
  }
}

// ---------------- LDS-staged agg inner loop (fp8 rows, 2-stage pipeline) ----
// Block's 32 nodes own a contiguous CSR slice. Stage src indices + as_
// scores into LDS; octet loop prefetches the NEXT batch's 4 h-row gathers
// before consuming the current batch (waits at vmcnt(4), not 0).
__device__ __forceinline__ void agg_block_stage(
    const uint2* __restrict__ h8v, const float* __restrict__ as_in,
    const int* __restrict__ csr_src, int* __restrict__ s_src,
    float* __restrict__ s_as, int t, int co,
    int e0, int eEnd, int rs, int re, float adn,
    float4& A0, float4& A1, float& den) {
  bool first = true;
  for (int cs = e0; cs < eEnd; cs += ECAP) {
    int ce = cs + ECAP; if (ce > eEnd) ce = eEnd;
    int cnt = ce - cs;
    if (!first) __syncthreads();  // protect LDS reuse across chunks
    first = false;
    for (int i = t; i < cnt; i += 512) {
      int s0 = csr_src[cs + i];
      bool has2 = (i + 256 < cnt);
      int s1 = has2 ? csr_src[cs + i + 256] : s0;
      float av0 = as_in[s0];
      float av1 = as_in[s1];
      s_src[i] = s0; s_as[i] = av0;
      if (has2) { s_src[i + 256] = s1; s_as[i + 256] = av1; }
    }
    __syncthreads();
    int a0 = rs > cs ? rs : cs;
    int a1 = re < ce ? re : ce;
    if (a0 >= a1) continue;  // barriers stay uniform (same dynamic count)

    auto loadhv = [&](int sb, uint2* hv) {
#pragma unroll
      for (int j = 0; j < 4; j++) {
        int sj = sb + j;
        int ii = ((sj < a1) ? sj : (a1 - 1)) - cs;
        hv[j] = h8v[(size_t)s_src[ii] * 8 + co];
      }
    };
    auto consume = [&](int sb, const uint2* hv) {
#pragma unroll
      for (int j = 0; j < 4; j++) {
        int sj = sb + j;
        int ii = ((sj < a1) ? sj : (a1 - 1)) - cs;
        float e = s_as[ii] + adn;
        e = fmaxf(e, 0.2f * e);  // leaky_relu(0.2)
        float c = (sj < a1) ? __expf(e) : 0.f;
        v2f f0 = __builtin_amdgcn_cvt_pk_f32_fp8(hv[j].x, false);
        v2f f1 = __builtin_amdgcn_cvt_pk_f32_fp8(hv[j].x, true);
        v2f f2 = __builtin_amdgcn_cvt_pk_f32_fp8(hv[j].y, false);
        v2f f3 = __builtin_amdgcn_cvt_pk_f32_fp8(hv[j].y, true);
        den += c;
        A0.x += c * f0[0]; A0.y += c * f0[1]; A0.z += c * f1[0]; A0.w += c * f1[1];
        A1.x += c * f2[0]; A1.y += c * f2[1]; A1.z += c * f3[0]; A1.w += c * f3[1];
      }
    };

    uint2 hvA[4];
    int s = a0;
    loadhv(s, hvA);
    for (s = a0 + 4; s < a1; s += 4) {
      uint2 hvB[4];
      loadhv(s, hvB);       // issue next batch before consuming current
      consume(s - 4, hvA);
#pragma unroll
      for (int j = 0; j < 4; j++) hvA[j] = hvB[j];
    }
    consume(s - 4, hvA);
  }
}

// finish one node: normalize + bias + relu -> 8 fp16
__device__ __forceinline__ void agg_finish(const float4& A0, const float4& A1,
                                           float den, const float* __restrict__ bprev,
                                           int co, _Float16* o) {
  float inv = 1.0f / (den + 1e-16f);
  float4 b0 = *(const float4*)&bprev[co * 8];
  float4 b1 = *(const float4*)&bprev[co * 8 + 4];
  o[0] = (_Float16)fmaxf(A0.x * inv + b0.x, 0.f);
  o[1] = (_Float16)fmaxf(A0.y * inv + b0.y, 0.f);
  o[2] = (_Float16)fmaxf(A0.z * inv + b0.z, 0.f);
  o[3] = (_Float16)fmaxf(A0.w * inv + b0.w, 0.f);
  o[4] = (_Float16)fmaxf(A1.x * inv + b1.x, 0.f);
  o[5] = (_Float16)fmaxf(A1.y * inv + b1.y, 0.f);
  o[6] = (_Float16)fmaxf(A1.z * inv + b1.z, 0.f);
  o[7] = (_Float16)fmaxf(A1.w * inv + b1.w, 0.f);
}

// ---------------- fused agg (layer L) + lin (layer L+1) ----------------
// Block = 32 nodes = two 16-node MFMA tiles. Phase A0: stage edge slice in
// LDS. Phase A: 4 waves aggregate 8 nodes each into padded LDS tile (fp16).
// Phase B: waves 0,1 run the 16x64x64 MFMA; h8/as/ad written for next layer.
__global__ __launch_bounds__(256) void agg_lin_kernel(
    const uint2* __restrict__ h8in, const float* __restrict__ as_in,
    const float* __restrict__ ad_in, const int* __restrict__ csr_src,
    const int* __restrict__ row_start, const float* __restrict__ bprev,
    const float* __restrict__ W, const float* __restrict__ a_src,
    const float* __restrict__ a_dst, unsigned char* __restrict__ h8out,
    float* __restrict__ as_out, float* __restrict__ ad_out, int N) {
  __shared__ int s_src[ECAP];
  __shared__ float s_as[ECAP];
  __shared__ _Float16 shh[32][72];     // agg output tile (padded)
  __shared__ _Float16 sht[2][16 * 72]; // phase-B transpose (wave-private)
  const int t = threadIdx.x;
  const int lane = t & 63, w = t >> 6;
  const int base = blockIdx.x * 32;

  // ---- phase A: aggregate 32 nodes (1 per octet), edges staged in LDS ----
  {
    const int ng = lane >> 3, co = lane & 7;
    const int ln = w * 8 + ng;
    int n = base + ln;
    int nc = (n < N) ? n : (N - 1);  // clamp: redundant work, guarded stores
    int rs = row_start[nc], re = row_start[nc + 1];
    float adn = ad_in[nc];
    int nend = base + 32; if (nend > N) nend = N;
    int e0 = row_start[base], eEnd = row_start[nend];
    float4 A0 = make_float4(0.f, 0.f, 0.f, 0.f);
    float4 A1 = make_float4(0.f, 0.f, 0.f, 0.f);
    float den = 0.f;
    agg_block_stage(h8in, as_in, csr_src, s_src, s_as, t, co,
                    e0, eEnd, rs, re, adn, A0, A1, den);
    _Float16 o[8];
    agg_finish(A0, A1, den, bprev, co, o);
    *(float4*)&shh[ln][co * 8] = *(float4*)o;
  }
  __syncthreads();
  if (w >= 2) return;

  // ---- phase B: lin for tile w (16 nodes), wave-per-tile ----
  const int col = lane & 15, quad = lane >> 4;
  half8 bf[4][2];
  float sa[4], sd[4];
#pragma unroll
  for (int nt = 0; nt < 4; nt++) {
#pragma unroll
    for (int kc = 0; kc < 2; kc++) {
      half8 v;
#pragma unroll
      for (int j = 0; j < 8; j++)
        v[j] = (_Float16)W[(kc * 32 + quad * 8 + j) * 64 + nt * 16 + col];
      bf[nt][kc] = v;
    }
    sa[nt] = a_src[nt * 16 + col];
    sd[nt] = a_dst[nt * 16 + col];
  }

  const int nb = base + w * 16;
  v4f acc[4];
#pragma unroll
  for (int nt = 0; nt < 4; nt++) acc[nt] = (v4f){0.f, 0.f, 0.f, 0.f};
#pragma unroll
  for (int kc = 0; kc < 2; kc++) {
    half8 a = *(const half8*)&shh[w * 16 + col][kc * 32 + quad * 8];
#pragma unroll
    for (int nt = 0; nt < 4; nt++)
      acc[nt] = __builtin_amdgcn_mfma_f32_16x16x32_f16(a, bf[nt][kc], acc[nt], 0, 0, 0);
  }

  float ps[4], pd[4];
#pragma unroll
  for (int r = 0; r < 4; r++) { ps[r] = 0.f; pd[r] = 0.f; }
#pragma unroll
  for (int nt = 0; nt < 4; nt++)
#pragma unroll
    for (int r = 0; r < 4; r++) {
      ps[r] += acc[nt][r] * sa[nt];
      pd[r] += acc[nt][r] * sd[nt];
    }
#pragma unroll
  for (int r = 0; r < 4; r++)
#pragma unroll
    for (int m = 1; m < 16; m <<= 1) {
      ps[r] += __shfl_xor(ps[r], m);
      pd[r] += __shfl_xor(pd[r], m);
    }
  if (col == 0) {
#pragma unroll
    for (int r = 0; r < 4; r++) {
      int node = nb + quad * 4 + r;
      if (node < N) { as_out[node] = ps[r]; ad_out[node] = pd[r]; }
    }
  }

#pragma unroll
  for (int nt = 0; nt < 4; nt++)
#pragma unroll
    for (int r = 0; r < 4; r++)
      sht[w][(quad * 4 + r) * 72 + nt * 16 + col] = (_Float16)acc[nt][r];
  int nr = lane >> 2, c4 = lane & 3;
  int node = nb + nr;
  if (node < N)
    store_row_fp8(&sht[w][nr * 72 + c4 * 16], h8out + (size_t)node * 64 + c4 * 16);
}

// ---------------- fused agg (layer 3) + global max pool + root ----------------
__global__ __launch_bounds__(256) void agg_pool_kernel(
    const uint2* __restrict__ h8in, const float* __restrict__ as_in,
    const float* __restrict__ ad_in, const int* __restrict__ csr_src,
    const int* __restrict__ row_start, const float* __restrict__ bprev,
    const int* __restrict__ batch, float* __restrict__ pool,
    int* __restrict__ root, int N) {
  __shared__ int s_src[ECAP];
  __shared__ float s_as[ECAP];
  __shared__ float red[4][64];
  const int t = threadIdx.x;
  const int lane = t & 63, w = t >> 6;
  const int ng = lane >> 3, co = lane & 7;
  const int ln = w * 8 + ng;
  const int base = blockIdx.x * 32;
  int n = base + ln;
  int nc = (n < N) ? n : (N - 1);
  int rs = row_start[nc], re = row_start[nc + 1];
  float adn = ad_in[nc];
  int nend = base + 32; if (nend > N) nend = N;
  int e0 = row_start[base], eEnd = row_start[nend];
  float4 A0 = make_float4(0.f, 0.f, 0.f, 0.f);
  float4 A1 = make_float4(0.f, 0.f, 0.f, 0.f);
  float den = 0.f;
  agg_block_stage(h8in, as_in, csr_src, s_src, s_as, t, co,
                  e0, eEnd, rs, re, adn, A0, A1, den);
  // round through fp16 to keep parity with the fp16 handoff path
  _Float16 o[8];
  agg_finish(A0, A1, den, bprev, co, o);
  float ov[8];
#pragma unroll
  for (int j = 0; j < 8; j++) ov[j] = (float)o[j];

  int g = batch[nc];
  if (co == 0 && n < N) {
    if (n == 0 || batch[n - 1] != g) atomicMin(&root[g], n);
  }

  int bstart = base;
  int bend = base + 31; if (bend >= N) bend = N - 1;
  int gfirst = batch[bstart];
  int glast = batch[bend];
  if (gfirst == glast) {
    // block covers one graph: reduce 32 nodes -> 64ch, one atomic/ch.
    // clamped lanes replay node N-1 into its own graph's max: no-op.
#pragma unroll
    for (int m = 8; m < 64; m <<= 1)
#pragma unroll
      for (int j = 0; j < 8; j++) ov[j] = fmaxf(ov[j], __shfl_xor(ov[j], m));
    if (ng == 0)
#pragma unroll
      for (int j = 0; j < 8; j++) red[w][co * 8 + j] = ov[j];
    __syncthreads();
    if (t < 64) {
      float m0 = fmaxf(red[0][t], red[1][t]);
      float m1 = fmaxf(red[2][t], red[3][t]);
      atomicMax((int*)&pool[(size_t)gfirst * 64 + t], __float_as_int(fmaxf(m0, m1)));
    }
  } else {
    // graph boundary inside block (~G blocks total): per-lane atomics
#pragma unroll
    for (int j = 0; j < 8; j++)
      if (n < N) atomicMax((int*)&pool[(size_t)g * 64 + co * 8 + j], __float_as_int(ov[j]));
  }
}

// ---------------- final fused MLP head (wave per graph) ----------------
__global__ void final_kernel(const float* __restrict__ pool, const int* __restrict__ root,
                             const float* __restrict__ x,
                             const float* __restrict__ lin0_W, const float* __restrict__ lin0_b,
                             const float* __restrict__ linnews_W, const float* __restrict__ linnews_b,
                             const float* __restrict__ lin1_W, const float* __restrict__ lin1_b,
                             float* __restrict__ out, int G, int N) {
  int t = threadIdx.x;
  int lane = t & 63, w = t >> 6;
  int g = blockIdx.x * 4 + w;
  if (g >= G) return;
  float hp = 0.f;
  for (int k = 0; k < 64; k++) hp += pool[(size_t)g * 64 + k] * lin0_W[k * 64 + lane];
  hp = fmaxf(hp + lin0_b[lane], 0.f);
  int r = root[g]; if (r > N - 1) r = N - 1; if (r < 0) r = 0;
  float nw = 0.f;
  for (int k = 0; k < 128; k++) nw += x[(size_t)r * 128 + k] * linnews_W[k * 64 + lane];
  nw = fmaxf(nw + linnews_b[lane], 0.f);
  float p = hp * lin1_W[lane] + nw * lin1_W[64 + lane];
  for (int k = 1; k < 64; k <<= 1) p += __shfl_xor(p, k);
  if (lane == 0) out[g] = 1.0f / (1.0f + __expf(-(p + lin1_b[0])));
}

// ---------------- launch ----------------
extern "C" void kernel_launch(void* const* d_in, const int* in_sizes, int n_in,
                              void* d_out, int out_size, void* d_ws, size_t ws_size,
                              hipStream_t stream) {
  (void)n_in; (void)ws_size;
  const float* x      = (const float*)d_in[0];
  const int*   adj    = (const int*)d_in[1];
  const int*   batch  = (const int*)d_in[2];
  const float* W1     = (const float*)d_in[3];
  const float* asrc1  = (const float*)d_in[4];
  const float* adst1  = (const float*)d_in[5];
  const float* b1     = (const float*)d_in[6];
  const float* W2     = (const float*)d_in[7];
  const float* asrc2  = (const float*)d_in[8];
  const float* adst2  = (const float*)d_in[9];
  const float* b2     = (const float*)d_in[10];
  const float* W3     = (const float*)d_in[11];
  const float* asrc3  = (const float*)d_in[12];
  const float* adst3  = (const float*)d_in[13];
  const float* b3     = (const float*)d_in[14];
  const float* lnW    = (const float*)d_in[15];
  const float* lnb    = (const float*)d_in[16];
  const float* l0W    = (const float*)d_in[17];
  const float* l0b    = (const float*)d_in[18];
  const float* l1W    = (const float*)d_in[19];
  const float* l1b    = (const float*)d_in[20];
  float* outp = (float*)d_out;

  const int N = in_sizes[2];
  const int E = in_sizes[1] / 2;
  const int Etot = E + N;
  const int G = out_size;
  const int B = (N + 255) / 256;  // real buckets (<= BPAD)

  const int* src_e = adj;
  const int* dst_e = adj + E;

  uintptr_t p = (uintptr_t)d_ws;
  auto alloc = [&](size_t bytes) -> void* {
    void* r = (void*)p;
    p += (bytes + 255) & ~(size_t)255;
    return r;
  };
  int*      hist      = (int*)alloc((size_t)BPAD * NBLK * 4);
  int*      row_start = (int*)alloc((size_t)(N + 1) * 4);
  int*      csr_src   = (int*)alloc((size_t)Etot * 4);
  unsigned int* ebuf  = (unsigned int*)alloc((size_t)E * 4);
  unsigned char* hA   = (unsigned char*)alloc((size_t)N * 64);  // h ping (fp8)
  unsigned char* hB   = (unsigned char*)alloc((size_t)N * 64);  // h pong (fp8)
  float*    asA       = (float*)alloc((size_t)N * 4);
  float*    adA       = (float*)alloc((size_t)N * 4);
  float*    asB       = (float*)alloc((size_t)N * 4);
  float*    adB       = (float*)alloc((size_t)N * 4);
  float*    pool      = (float*)alloc((size_t)G * 64 * 4);
  int*      root      = (int*)alloc((size_t)G * 4);

  int chunk = (E + NBLK - 1) / NBLK;
  const int ntiles = (N + 15) >> 4;
  const int nlw = LINB * 4;
  const int c1 = ntiles / 4, c2 = ntiles / 2, c3 = (3 * ntiles) / 4;

  // CSR chain, each stage backfilled with a quarter of lin1's tiles
  hist_lin_kernel<<<dim3(NBLK + LINB), dim3(256), 0, stream>>>(
      dst_e, hist, E, chunk, pool, root, G,
      x, W1, asrc1, adst1, hA, asA, adA, N, 0, c1, nlw);
  hscan_lin_kernel<<<dim3(1 + LINB), dim3(256), 0, stream>>>(
      hist, x, W1, asrc1, adst1, hA, asA, adA, N, c1, c2, nlw);
  scatter_lin_kernel<<<dim3(NBLK + LINB), dim3(256), 0, stream>>>(
      src_e, dst_e, hist, ebuf, E, chunk,
      x, W1, asrc1, adst1, hA, asA, adA, N, c2, c3, nlw);
  build_lin_kernel<<<dim3(B + LINB), dim3(256), 0, stream>>>(
      ebuf, hist, row_start, csr_src, N, E, B,
      x, W1, asrc1, adst1, hA, asA, adA, N, c3, ntiles, nlw);

  const int aggGrid = (N + 31) / 32;

  // agg1 + lin2 fused (ping -> pong)
  agg_lin_kernel<<<dim3(aggGrid), dim3(256), 0, stream>>>(
      (const uint2*)hA, asA, adA, csr_src, row_start, b1, W2, asrc2, adst2, hB, asB, adB, N);
  // agg2 + lin3 fused (pong -> ping)
  agg_lin_kernel<<<dim3(aggGrid), dim3(256), 0, stream>>>(
      (const uint2*)hB, asB, adB, csr_src, row_start, b2, W3, asrc3, adst3, hA, asA, adA, N);
  // agg3 + pool + root fused
  agg_pool_kernel<<<dim3(aggGrid), dim3(256), 0, stream>>>(
      (const uint2*)hA, asA, adA, csr_src, row_start, b3, batch, pool, root, N);

  // head
  final_kernel<<<dim3((G + 3) / 4), dim3(256), 0, stream>>>(
      pool, root, x, l0W, l0b, lnW, lnb, l1W, l1b, outp, G, N);
}